// Round 4
// baseline (2112.350 us; speedup 1.0000x reference)
//
#include <hip/hip_runtime.h>
#include <hip/hip_bf16.h>

static constexpr int Bn = 32;
static constexpr int Hin = 256, Win = 256;
static constexpr int C1 = 64, H1 = 128, W1 = 128;
static constexpr int C2 = 32, H2 = 64, W2 = 64;
static constexpr int Dd = 64;    // latent dim
static constexpr int Kc = 512;   // codebook entries
static constexpr int ROWS = Bn * H2 * W2;  // 131072

// ws layout (floats): lossA(64) | idx(131072 ints) | k2a(73728) | k2b(6912) | chunk
static constexpr int K2A_FLOATS = 64 * 32 * 36;  // 73728
static constexpr int K2B_FLOATS = 3 * 64 * 36;   // 6912
static constexpr int FIX_FLOATS = 64 + ROWS + K2A_FLOATS + K2B_FLOATS + 64;
static constexpr int H1_PER_N = C1 * H1 * W1;    // 1,048,576
static constexpr int Z_PER_N  = H2 * W2 * Dd;    // 262,144
static constexpr int H2_PER_N = C2 * H2 * W2;    // 131,072

__global__ void k_zero(float* p) { p[threadIdx.x] = 0.f; }

// ---------- upsample-conv weight compose: K'[py,px] = Ay^T W Ax ----------
__global__ __launch_bounds__(256) void k_wtrans(
    const float* __restrict__ w, float* __restrict__ k2, int N)
{
  int i = blockIdx.x * 256 + threadIdx.x;
  if (i >= N) return;
  float W[3][3];
#pragma unroll
  for (int ty = 0; ty < 3; ++ty)
#pragma unroll
    for (int tx = 0; tx < 3; ++tx) W[ty][tx] = w[i * 9 + ty * 3 + tx];
  const float A[2][3][3] = {
      {{.75f, .25f, 0.f}, {.25f, .75f, 0.f}, {0.f, .75f, .25f}},
      {{.25f, .75f, 0.f}, {0.f, .75f, .25f}, {0.f, .25f, .75f}}};
#pragma unroll
  for (int py = 0; py < 2; ++py)
#pragma unroll
    for (int px = 0; px < 2; ++px)
#pragma unroll
      for (int a = 0; a < 3; ++a)
#pragma unroll
        for (int b = 0; b < 3; ++b) {
          float v = 0.f;
#pragma unroll
          for (int ty = 0; ty < 3; ++ty)
#pragma unroll
            for (int tx = 0; tx < 3; ++tx)
              v += W[ty][tx] * A[py][ty][a] * A[px][tx][b];
          k2[(size_t)i * 36 + (py * 2 + px) * 9 + a * 3 + b] = v;
        }
}

// ---------- enc conv1: 3->64, 3x3, s2, p1, ReLU ----------
__global__ __launch_bounds__(256) void k_conv1(
    const float* __restrict__ x, const float* __restrict__ w,
    const float* __restrict__ b, float* __restrict__ h1, int n0)
{
  int bid = blockIdx.x;
  int xt = bid & 1, yt = (bid >> 1) & 15, cc = (bid >> 5) & 3, n = bid >> 7;
  int X0 = xt * 64, Y0 = yt * 8, co0 = cc * 16;
  __shared__ float sIn[3][17][130];
  int tid = threadIdx.x;
  for (int i = tid; i < 3 * 17 * 130; i += 256) {
    int ci = i / (17 * 130);
    int rr = (i / 130) % 17;
    int ccx = i % 130;
    int gy = 2 * Y0 - 1 + rr, gx = 2 * X0 - 1 + ccx;
    float v = 0.f;
    if (gy >= 0 && gy < Hin && gx >= 0 && gx < Win)
      v = x[(((size_t)(n0 + n) * 3 + ci) * Hin + gy) * Win + gx];
    sIn[ci][rr][ccx] = v;
  }
  __syncthreads();
  int lx = tid & 63, ys = tid >> 6;
  float acc[16][2];
#pragma unroll
  for (int c = 0; c < 16; ++c) { acc[c][0] = 0.f; acc[c][1] = 0.f; }
#pragma unroll
  for (int ci = 0; ci < 3; ++ci)
#pragma unroll
    for (int ky = 0; ky < 3; ++ky)
#pragma unroll
      for (int kx = 0; kx < 3; ++kx) {
        float u0 = sIn[ci][2 * ys + ky][2 * lx + kx];
        float u1 = sIn[ci][2 * ys + 8 + ky][2 * lx + kx];
#pragma unroll
        for (int c = 0; c < 16; ++c) {
          float wv = w[((co0 + c) * 3 + ci) * 9 + ky * 3 + kx];
          acc[c][0] += u0 * wv;
          acc[c][1] += u1 * wv;
        }
      }
#pragma unroll
  for (int c = 0; c < 16; ++c) {
    float bv = b[co0 + c];
    float v0 = acc[c][0] + bv; v0 = v0 > 0.f ? v0 : 0.f;
    float v1 = acc[c][1] + bv; v1 = v1 > 0.f ? v1 : 0.f;
    h1[((n * C1 + co0 + c) * H1 + Y0 + ys) * W1 + X0 + lx] = v0;
    h1[((n * C1 + co0 + c) * H1 + Y0 + ys + 4) * W1 + X0 + lx] = v1;
  }
}

// ---------- enc conv2: 64->32, 3x3, s2, p1, ReLU ----------
__global__ __launch_bounds__(256) void k_conv2(
    const float* __restrict__ h1, const float* __restrict__ w,
    const float* __restrict__ b, float* __restrict__ h2)
{
  int bid = blockIdx.x;
  int yt = bid & 7, cc = (bid >> 3) & 1, n = bid >> 4;
  int Y0 = yt * 8, co0 = cc * 16;
  __shared__ float sIn[4][17][130];
  int tid = threadIdx.x;
  int lx = tid & 63, ys = tid >> 6;
  float acc[16][2];
#pragma unroll
  for (int c = 0; c < 16; ++c) { acc[c][0] = 0.f; acc[c][1] = 0.f; }
  for (int cb0 = 0; cb0 < C1; cb0 += 4) {
    __syncthreads();
    for (int i = tid; i < 4 * 17 * 130; i += 256) {
      int ci = i / (17 * 130);
      int rr = (i / 130) % 17;
      int ccx = i % 130;
      int gy = 2 * Y0 - 1 + rr, gx = -1 + ccx;
      float v = 0.f;
      if (gy >= 0 && gy < H1 && gx >= 0 && gx < W1)
        v = h1[((n * C1 + cb0 + ci) * H1 + gy) * W1 + gx];
      sIn[ci][rr][ccx] = v;
    }
    __syncthreads();
#pragma unroll
    for (int ci = 0; ci < 4; ++ci)
#pragma unroll
      for (int ky = 0; ky < 3; ++ky)
#pragma unroll
        for (int kx = 0; kx < 3; ++kx) {
          float u0 = sIn[ci][2 * ys + ky][2 * lx + kx];
          float u1 = sIn[ci][2 * ys + 8 + ky][2 * lx + kx];
#pragma unroll
          for (int c = 0; c < 16; ++c) {
            float wv = w[((co0 + c) * C1 + cb0 + ci) * 9 + ky * 3 + kx];
            acc[c][0] += u0 * wv;
            acc[c][1] += u1 * wv;
          }
        }
  }
#pragma unroll
  for (int c = 0; c < 16; ++c) {
    float bv = b[co0 + c];
    float v0 = acc[c][0] + bv; v0 = v0 > 0.f ? v0 : 0.f;
    float v1 = acc[c][1] + bv; v1 = v1 > 0.f ? v1 : 0.f;
    h2[((n * C2 + co0 + c) * H2 + Y0 + ys) * W2 + lx] = v0;
    h2[((n * C2 + co0 + c) * H2 + Y0 + ys + 4) * W2 + lx] = v1;
  }
}

// ---------- enc conv3 (1x1, 32->64) -> z in [row][64] ----------
__global__ __launch_bounds__(256) void k_conv3z(
    const float* __restrict__ h2, const float* __restrict__ w,
    const float* __restrict__ b, float* __restrict__ z)
{
  int bid = blockIdx.x;
  int y = bid & 63, n = bid >> 6;
  __shared__ float sH[C2][64];
  __shared__ float sW[Dd * 33];
  int tid = threadIdx.x;
  for (int i = tid; i < C2 * 64; i += 256) {
    int ci = i >> 6, xx = i & 63;
    sH[ci][xx] = h2[((n * C2 + ci) * H2 + y) * W2 + xx];
  }
  for (int i = tid; i < Dd * C2; i += 256) {
    int d = i >> 5, ci = i & 31;
    sW[d * 33 + ci] = w[i];
  }
  __syncthreads();
  int dg = tid & 3, lx = tid >> 2;
  float acc[16];
#pragma unroll
  for (int j = 0; j < 16; ++j) acc[j] = 0.f;
  for (int ci = 0; ci < C2; ++ci) {
    float u = sH[ci][lx];
#pragma unroll
    for (int j = 0; j < 16; ++j)
      acc[j] += u * sW[(dg * 16 + j) * 33 + ci];
  }
  int row = (n * H2 + y) * W2 + lx;
#pragma unroll
  for (int j = 0; j < 16; ++j)
    z[row * Dd + dg * 16 + j] = acc[j] + b[dg * 16 + j];
}

// ---------- VQ: argmin + loss ----------
__global__ __launch_bounds__(256) void k_vq(
    const float* __restrict__ z, const float* __restrict__ cbf,
    int* __restrict__ idx, float* __restrict__ lossA, int row0)
{
  __shared__ float c2s[Kc];
  int tid = threadIdx.x;
  for (int c = tid; c < Kc; c += 256) {
    float s = 0.f;
#pragma unroll
    for (int d = 0; d < Dd; ++d) { float v = cbf[c * Dd + d]; s += v * v; }
    c2s[c] = s;
  }
  __syncthreads();
  int r = blockIdx.x * 256 + tid;
  float4 zr[16];
  const float4* zp = (const float4*)(z + (size_t)r * Dd);
#pragma unroll
  for (int i = 0; i < 16; ++i) zr[i] = zp[i];
  float best = 1e30f; int bidx = 0;
  for (int c = 0; c < Kc; ++c) {
    const float* __restrict__ cr = cbf + c * Dd;
    float d0 = 0.f, d1 = 0.f, d2a = 0.f, d3 = 0.f;
#pragma unroll
    for (int i = 0; i < 16; ++i) {
      d0 += zr[i].x * cr[4 * i + 0];
      d1 += zr[i].y * cr[4 * i + 1];
      d2a += zr[i].z * cr[4 * i + 2];
      d3 += zr[i].w * cr[4 * i + 3];
    }
    float dot = (d0 + d1) + (d2a + d3);
    float dist = c2s[c] - 2.f * dot;
    if (dist < best) { best = dist; bidx = c; }
  }
  idx[row0 + r] = bidx;
  const float* cr = cbf + bidx * Dd;
  float ls = 0.f;
#pragma unroll
  for (int i = 0; i < 16; ++i) {
    float e0 = zr[i].x - cr[4 * i + 0];
    float e1 = zr[i].y - cr[4 * i + 1];
    float e2 = zr[i].z - cr[4 * i + 2];
    float e3 = zr[i].w - cr[4 * i + 3];
    ls += e0 * e0 + e1 * e1 + e2 * e2 + e3 * e3;
  }
#pragma unroll
  for (int off = 32; off > 0; off >>= 1) ls += __shfl_down(ls, off);
  if ((tid & 63) == 0) atomicAdd(lossA, ls);
}

__global__ void k_loss_final(const float* __restrict__ a, float* __restrict__ out)
{
  if (threadIdx.x == 0) {
    float l = a[0] / (float)(ROWS * Dd);
    out[0] = l;
    out[1] = l;
  }
}

// ---------- dec conv1 (1x1, 64->32, ReLU) ----------
__global__ __launch_bounds__(256) void k_dec1(
    const int* __restrict__ idx, const float* __restrict__ cbf,
    const float* __restrict__ w, const float* __restrict__ b,
    float* __restrict__ d1, int row0)
{
  int bid = blockIdx.x;
  int y = bid & 63, n = bid >> 6;
  __shared__ float sZ[64 * 65];
  __shared__ float sW[32 * 65];
  int tid = threadIdx.x;
  int base = row0 + (n * H2 + y) * W2;
  {
    int d = tid & 63, x0 = tid >> 6;
    for (int k = 0; k < 16; ++k) {
      int xx = x0 + 4 * k;
      int ci = idx[base + xx];
      sZ[xx * 65 + d] = cbf[ci * Dd + d];
    }
  }
  for (int i = tid; i < 32 * Dd; i += 256) {
    int co = i >> 6, d = i & 63;
    sW[co * 65 + d] = w[i];
  }
  __syncthreads();
  int lx = tid & 63, cg = tid >> 6;
  float acc[8];
#pragma unroll
  for (int j = 0; j < 8; ++j) acc[j] = 0.f;
  for (int d = 0; d < Dd; ++d) {
    float u = sZ[lx * 65 + d];
#pragma unroll
    for (int j = 0; j < 8; ++j)
      acc[j] += u * sW[(cg * 8 + j) * 65 + d];
  }
#pragma unroll
  for (int j = 0; j < 8; ++j) {
    int co = cg * 8 + j;
    float v = acc[j] + b[co];
    v = v > 0.f ? v : 0.f;
    d1[((n * C2 + co) * H2 + y) * W2 + lx] = v;
  }
}

// ---------- composed upsample2x+conv3x3 as 4-phase conv on low-res grid ----------
// Interior-exact with clamped halo; output ring (rows 0,Ho-1 / cols 0,Wo-1)
// is overwritten by k_upfix (zero-pad of U at conv border).
template <int Ci, int Hi, int Co, int COCH, bool RELU>
__global__ __launch_bounds__(256) void k_upconv2x(
    const float* __restrict__ I, const float* __restrict__ k2,
    const float* __restrict__ bias, float* __restrict__ O, int n0)
{
  constexpr int TT = Hi / 16, NCG = Co / COCH, Ho = 2 * Hi, Wo = 2 * Hi;
  int bid = blockIdx.x;
  int tx = bid % TT; bid /= TT;
  int ty = bid % TT; bid /= TT;
  int cg = bid % NCG; bid /= NCG;
  int n = bid;
  int Y0 = ty * 16, X0 = tx * 16;
  __shared__ float sI[4][18 * 19];
  int tid = threadIdx.x;
  int lx = tid & 15, ly = tid >> 4;
  float acc[COCH][4];
#pragma unroll
  for (int j = 0; j < COCH; ++j)
#pragma unroll
    for (int ph = 0; ph < 4; ++ph) acc[j][ph] = 0.f;
  const float* kbase = k2 + (size_t)cg * COCH * Ci * 36;
  for (int c0 = 0; c0 < Ci; c0 += 4) {
    __syncthreads();
    for (int i = tid; i < 4 * 18 * 18; i += 256) {
      int s = i / 324, r2 = i % 324;
      int rr = r2 / 18, cc = r2 % 18;
      int gy = Y0 - 1 + rr; gy = gy < 0 ? 0 : (gy > Hi - 1 ? Hi - 1 : gy);
      int gx = X0 - 1 + cc; gx = gx < 0 ? 0 : (gx > Hi - 1 ? Hi - 1 : gx);
      sI[s][rr * 19 + cc] = I[((size_t)n * Ci + c0 + s) * Hi * Hi + gy * Hi + gx];
    }
    __syncthreads();
    float t[4][9];
#pragma unroll
    for (int s = 0; s < 4; ++s)
#pragma unroll
      for (int dy = 0; dy < 3; ++dy)
#pragma unroll
        for (int dx = 0; dx < 3; ++dx)
          t[s][dy * 3 + dx] = sI[s][(ly + dy) * 19 + lx + dx];
#pragma unroll
    for (int j = 0; j < COCH; ++j) {
      const float* kj = kbase + ((size_t)j * Ci + c0) * 36;
#pragma unroll
      for (int s = 0; s < 4; ++s)
#pragma unroll
        for (int ph = 0; ph < 4; ++ph)
#pragma unroll
          for (int tp = 0; tp < 9; ++tp)
            acc[j][ph] += t[s][tp] * kj[s * 36 + ph * 9 + tp];
    }
  }
  int oy = 2 * (Y0 + ly), ox = 2 * (X0 + lx);
#pragma unroll
  for (int j = 0; j < COCH; ++j) {
    int co = cg * COCH + j;
    float bv = bias[co];
#pragma unroll
    for (int py = 0; py < 2; ++py) {
      float2 v;
      v.x = acc[j][py * 2 + 0] + bv;
      v.y = acc[j][py * 2 + 1] + bv;
      if (RELU) { v.x = v.x > 0.f ? v.x : 0.f; v.y = v.y > 0.f ? v.y : 0.f; }
      size_t off = ((size_t)((n0 + n) * Co + co) * Ho + oy + py) * Wo + ox;
      *(float2*)&O[off] = v;
    }
  }
}

// ---------- exact direct computation of the output border ring ----------
template <int Ci, int Hi, int Co, int CG, bool RELU>
__global__ __launch_bounds__(256) void k_upfix(
    const float* __restrict__ I, const float* __restrict__ w,
    const float* __restrict__ bias, float* __restrict__ O, int CHn, int n0)
{
  constexpr int Ho = 2 * Hi, Wo = 2 * Hi;
  constexpr int RING = 2 * (Ho + Wo) - 4;
  constexpr int NCG = Co / CG;
  int gi = blockIdx.x * 256 + threadIdx.x;
  if (gi >= CHn * NCG * RING) return;
  int p = gi % RING;
  int cgrp = (gi / RING) % NCG;
  int n = gi / (RING * NCG);
  int u, v;
  if (p < Wo)            { u = 0;       v = p; }
  else if (p < 2 * Wo)   { u = Ho - 1;  v = p - Wo; }
  else { int q = p - 2 * Wo; u = 1 + (q >> 1); v = (q & 1) ? (Wo - 1) : 0; }
  float acc[CG];
#pragma unroll
  for (int j = 0; j < CG; ++j) acc[j] = 0.f;
  for (int ci = 0; ci < Ci; ++ci) {
    const float* Ip = I + ((size_t)n * Ci + ci) * Hi * Hi;
    float U[9];
#pragma unroll
    for (int dy = 0; dy < 3; ++dy)
#pragma unroll
      for (int dx = 0; dx < 3; ++dx) {
        int vy = u - 1 + dy, vx = v - 1 + dx;
        float val = 0.f;
        if (vy >= 0 && vy < Ho && vx >= 0 && vx < Wo) {
          int ky0, ky1, kx0, kx1; float ay0, ax0;
          if (vy & 1) { ky0 = vy >> 1; ky1 = ky0 + 1; ay0 = .75f; }
          else        { ky1 = vy >> 1; ky0 = ky1 - 1; ay0 = .25f; }
          if (vx & 1) { kx0 = vx >> 1; kx1 = kx0 + 1; ax0 = .75f; }
          else        { kx1 = vx >> 1; kx0 = kx1 - 1; ax0 = .25f; }
          ky0 = ky0 < 0 ? 0 : (ky0 > Hi - 1 ? Hi - 1 : ky0);
          ky1 = ky1 < 0 ? 0 : (ky1 > Hi - 1 ? Hi - 1 : ky1);
          kx0 = kx0 < 0 ? 0 : (kx0 > Hi - 1 ? Hi - 1 : kx0);
          kx1 = kx1 < 0 ? 0 : (kx1 > Hi - 1 ? Hi - 1 : kx1);
          float ay1 = 1.f - ay0, ax1 = 1.f - ax0;
          float r0 = ax0 * Ip[ky0 * Hi + kx0] + ax1 * Ip[ky0 * Hi + kx1];
          float r1 = ax0 * Ip[ky1 * Hi + kx0] + ax1 * Ip[ky1 * Hi + kx1];
          val = ay0 * r0 + ay1 * r1;
        }
        U[dy * 3 + dx] = val;
      }
#pragma unroll
    for (int j = 0; j < CG; ++j) {
      const float* wp = w + ((size_t)(cgrp * CG + j) * Ci + ci) * 9;
#pragma unroll
      for (int tp = 0; tp < 9; ++tp) acc[j] += U[tp] * wp[tp];
    }
  }
#pragma unroll
  for (int j = 0; j < CG; ++j) {
    int co = cgrp * CG + j;
    float val = acc[j] + bias[co];
    if (RELU) val = val > 0.f ? val : 0.f;
    O[((size_t)((n0 + n) * Co + co) * Ho + u) * Wo + v] = val;
  }
}

extern "C" void kernel_launch(void* const* d_in, const int* in_sizes, int n_in,
                              void* d_out, int out_size, void* d_ws, size_t ws_size,
                              hipStream_t stream)
{
  const float* x      = (const float*)d_in[0];
  const float* cb     = (const float*)d_in[1];
  const float* enc_w1 = (const float*)d_in[2];
  const float* enc_b1 = (const float*)d_in[3];
  const float* enc_w2 = (const float*)d_in[4];
  const float* enc_b2 = (const float*)d_in[5];
  const float* enc_w3 = (const float*)d_in[6];
  const float* enc_b3 = (const float*)d_in[7];
  const float* dec_w1 = (const float*)d_in[8];
  const float* dec_b1 = (const float*)d_in[9];
  const float* dec_w2 = (const float*)d_in[10];
  const float* dec_b2 = (const float*)d_in[11];
  const float* dec_w3 = (const float*)d_in[12];
  const float* dec_b3 = (const float*)d_in[13];

  float* ws = (float*)d_ws;
  float* lossA = ws;                      // 64
  int* idx = (int*)(lossA + 64);          // ROWS ints
  float* k2a = (float*)(idx + ROWS);      // 73728
  float* k2b = k2a + K2A_FLOATS;          // 6912
  float* chunkbuf = k2b + K2B_FLOATS + 64;

  int CH = 1;
  for (int c = 32; c >= 1; c >>= 1) {
    size_t need = ((size_t)FIX_FLOATS + (size_t)(H1_PER_N + Z_PER_N + H2_PER_N) * c) * 4;
    if (need <= ws_size) { CH = c; break; }
  }
  float* h1 = chunkbuf;                   // CH * 1,048,576  (reused as d2)
  float* z  = h1 + (size_t)H1_PER_N * CH; // CH * 262,144
  float* h2 = z + (size_t)Z_PER_N * CH;   // CH * 131,072    (reused as d1)

  k_zero<<<1, 64, 0, stream>>>(lossA);
  k_wtrans<<<(64 * 32 + 255) / 256, 256, 0, stream>>>(dec_w2, k2a, 64 * 32);
  k_wtrans<<<1, 256, 0, stream>>>(dec_w3, k2b, 3 * 64);

  float* out = (float*)d_out;

  for (int n0 = 0; n0 < Bn; n0 += CH) {
    int row0 = n0 * H2 * W2;
    k_conv1<<<CH * 128, 256, 0, stream>>>(x, enc_w1, enc_b1, h1, n0);
    k_conv2<<<CH * 16, 256, 0, stream>>>(h1, enc_w2, enc_b2, h2);
    k_conv3z<<<CH * 64, 256, 0, stream>>>(h2, enc_w3, enc_b3, z);
    k_vq<<<CH * 16, 256, 0, stream>>>(z, cb, idx, lossA, row0);
    k_dec1<<<CH * 64, 256, 0, stream>>>(idx, cb, dec_w1, dec_b1, h2, row0);
    // d1 (h2) -> d2 (h1): 32ch 64x64 -> 64ch 128x128, ReLU
    k_upconv2x<32, 64, 64, 8, true><<<CH * 8 * 4 * 4, 256, 0, stream>>>(
        h2, k2a, dec_b2, h1, 0);
    k_upfix<32, 64, 64, 16, true>
        <<<(CH * 4 * 508 + 255) / 256, 256, 0, stream>>>(
            h2, dec_w2, dec_b2, h1, CH, 0);
    // d2 (h1) -> recon: 64ch 128x128 -> 3ch 256x256, f32 out at offset 2
    k_upconv2x<64, 128, 3, 3, false><<<CH * 1 * 8 * 8, 256, 0, stream>>>(
        h1, k2b, dec_b3, out + 2, n0);
    k_upfix<64, 128, 3, 3, false>
        <<<(CH * 1 * 1020 + 255) / 256, 256, 0, stream>>>(
            h1, dec_w3, dec_b3, out + 2, CH, n0);
  }
  k_loss_final<<<1, 64, 0, stream>>>(lossA, out);
}

// Round 5
// 2056.083 us; speedup vs baseline: 1.0274x; 1.0274x over previous
//
#include <hip/hip_runtime.h>
#include <hip/hip_bf16.h>

static constexpr int Bn = 32;
static constexpr int Hin = 256, Win = 256;
static constexpr int C1 = 64, H1 = 128, W1 = 128;
static constexpr int C2 = 32, H2 = 64, W2 = 64;
static constexpr int Dd = 64;    // latent dim
static constexpr int Kc = 512;   // codebook entries
static constexpr int ROWS = Bn * H2 * W2;  // 131072

// ws layout (floats): lossA(64) | idx(131072 ints) | k2a(73728) | k2b(6912) | chunk
static constexpr int K2A_FLOATS = 64 * 32 * 36;  // 73728
static constexpr int K2B_FLOATS = 3 * 64 * 36;   // 6912
static constexpr int FIX_FLOATS = 64 + ROWS + K2A_FLOATS + K2B_FLOATS + 64;
static constexpr int H1_PER_N = C1 * H1 * W1;    // 1,048,576
static constexpr int Z_PER_N  = H2 * W2 * Dd;    // 262,144
static constexpr int H2_PER_N = C2 * H2 * W2;    // 131,072

__global__ void k_zero(float* p) { p[threadIdx.x] = 0.f; }

// ---------- upsample-conv weight compose: K'[py,px] = Ay^T W Ax ----------
__global__ __launch_bounds__(256) void k_wtrans(
    const float* __restrict__ w, float* __restrict__ k2, int N)
{
  int i = blockIdx.x * 256 + threadIdx.x;
  if (i >= N) return;
  float W[3][3];
#pragma unroll
  for (int ty = 0; ty < 3; ++ty)
#pragma unroll
    for (int tx = 0; tx < 3; ++tx) W[ty][tx] = w[i * 9 + ty * 3 + tx];
  const float A[2][3][3] = {
      {{.75f, .25f, 0.f}, {.25f, .75f, 0.f}, {0.f, .75f, .25f}},
      {{.25f, .75f, 0.f}, {0.f, .75f, .25f}, {0.f, .25f, .75f}}};
#pragma unroll
  for (int py = 0; py < 2; ++py)
#pragma unroll
    for (int px = 0; px < 2; ++px)
#pragma unroll
      for (int a = 0; a < 3; ++a)
#pragma unroll
        for (int b = 0; b < 3; ++b) {
          float v = 0.f;
#pragma unroll
          for (int ty = 0; ty < 3; ++ty)
#pragma unroll
            for (int tx = 0; tx < 3; ++tx)
              v += W[ty][tx] * A[py][ty][a] * A[px][tx][b];
          k2[(size_t)i * 36 + (py * 2 + px) * 9 + a * 3 + b] = v;
        }
}

// ---------- enc conv1: 3->64, 3x3, s2, p1, ReLU ----------
__global__ __launch_bounds__(256) void k_conv1(
    const float* __restrict__ x, const float* __restrict__ w,
    const float* __restrict__ b, float* __restrict__ h1, int n0)
{
  int bid = blockIdx.x;
  int xt = bid & 1, yt = (bid >> 1) & 15, cc = (bid >> 5) & 3, n = bid >> 7;
  int X0 = xt * 64, Y0 = yt * 8, co0 = cc * 16;
  __shared__ float sIn[3][17][130];
  int tid = threadIdx.x;
  for (int i = tid; i < 3 * 17 * 130; i += 256) {
    int ci = i / (17 * 130);
    int rr = (i / 130) % 17;
    int ccx = i % 130;
    int gy = 2 * Y0 - 1 + rr, gx = 2 * X0 - 1 + ccx;
    float v = 0.f;
    if (gy >= 0 && gy < Hin && gx >= 0 && gx < Win)
      v = x[(((size_t)(n0 + n) * 3 + ci) * Hin + gy) * Win + gx];
    sIn[ci][rr][ccx] = v;
  }
  __syncthreads();
  int lx = tid & 63, ys = tid >> 6;
  float acc[16][2];
#pragma unroll
  for (int c = 0; c < 16; ++c) { acc[c][0] = 0.f; acc[c][1] = 0.f; }
#pragma unroll
  for (int ci = 0; ci < 3; ++ci)
#pragma unroll
    for (int ky = 0; ky < 3; ++ky)
#pragma unroll
      for (int kx = 0; kx < 3; ++kx) {
        float u0 = sIn[ci][2 * ys + ky][2 * lx + kx];
        float u1 = sIn[ci][2 * ys + 8 + ky][2 * lx + kx];
#pragma unroll
        for (int c = 0; c < 16; ++c) {
          float wv = w[((co0 + c) * 3 + ci) * 9 + ky * 3 + kx];
          acc[c][0] += u0 * wv;
          acc[c][1] += u1 * wv;
        }
      }
#pragma unroll
  for (int c = 0; c < 16; ++c) {
    float bv = b[co0 + c];
    float v0 = acc[c][0] + bv; v0 = v0 > 0.f ? v0 : 0.f;
    float v1 = acc[c][1] + bv; v1 = v1 > 0.f ? v1 : 0.f;
    h1[((n * C1 + co0 + c) * H1 + Y0 + ys) * W1 + X0 + lx] = v0;
    h1[((n * C1 + co0 + c) * H1 + Y0 + ys + 4) * W1 + X0 + lx] = v1;
  }
}

// ---------- enc conv2: 64->32, 3x3, s2, p1, ReLU ----------
__global__ __launch_bounds__(256) void k_conv2(
    const float* __restrict__ h1, const float* __restrict__ w,
    const float* __restrict__ b, float* __restrict__ h2)
{
  int bid = blockIdx.x;
  int yt = bid & 7, cc = (bid >> 3) & 1, n = bid >> 4;
  int Y0 = yt * 8, co0 = cc * 16;
  __shared__ float sIn[4][17][130];
  int tid = threadIdx.x;
  int lx = tid & 63, ys = tid >> 6;
  float acc[16][2];
#pragma unroll
  for (int c = 0; c < 16; ++c) { acc[c][0] = 0.f; acc[c][1] = 0.f; }
  for (int cb0 = 0; cb0 < C1; cb0 += 4) {
    __syncthreads();
    for (int i = tid; i < 4 * 17 * 130; i += 256) {
      int ci = i / (17 * 130);
      int rr = (i / 130) % 17;
      int ccx = i % 130;
      int gy = 2 * Y0 - 1 + rr, gx = -1 + ccx;
      float v = 0.f;
      if (gy >= 0 && gy < H1 && gx >= 0 && gx < W1)
        v = h1[((n * C1 + cb0 + ci) * H1 + gy) * W1 + gx];
      sIn[ci][rr][ccx] = v;
    }
    __syncthreads();
#pragma unroll
    for (int ci = 0; ci < 4; ++ci)
#pragma unroll
      for (int ky = 0; ky < 3; ++ky)
#pragma unroll
        for (int kx = 0; kx < 3; ++kx) {
          float u0 = sIn[ci][2 * ys + ky][2 * lx + kx];
          float u1 = sIn[ci][2 * ys + 8 + ky][2 * lx + kx];
#pragma unroll
          for (int c = 0; c < 16; ++c) {
            float wv = w[((co0 + c) * C1 + cb0 + ci) * 9 + ky * 3 + kx];
            acc[c][0] += u0 * wv;
            acc[c][1] += u1 * wv;
          }
        }
  }
#pragma unroll
  for (int c = 0; c < 16; ++c) {
    float bv = b[co0 + c];
    float v0 = acc[c][0] + bv; v0 = v0 > 0.f ? v0 : 0.f;
    float v1 = acc[c][1] + bv; v1 = v1 > 0.f ? v1 : 0.f;
    h2[((n * C2 + co0 + c) * H2 + Y0 + ys) * W2 + lx] = v0;
    h2[((n * C2 + co0 + c) * H2 + Y0 + ys + 4) * W2 + lx] = v1;
  }
}

// ---------- enc conv3 (1x1, 32->64) -> z in [row][64] ----------
__global__ __launch_bounds__(256) void k_conv3z(
    const float* __restrict__ h2, const float* __restrict__ w,
    const float* __restrict__ b, float* __restrict__ z)
{
  int bid = blockIdx.x;
  int y = bid & 63, n = bid >> 6;
  __shared__ float sH[C2][64];
  __shared__ float sW[Dd * 33];
  int tid = threadIdx.x;
  for (int i = tid; i < C2 * 64; i += 256) {
    int ci = i >> 6, xx = i & 63;
    sH[ci][xx] = h2[((n * C2 + ci) * H2 + y) * W2 + xx];
  }
  for (int i = tid; i < Dd * C2; i += 256) {
    int d = i >> 5, ci = i & 31;
    sW[d * 33 + ci] = w[i];
  }
  __syncthreads();
  int dg = tid & 3, lx = tid >> 2;
  float acc[16];
#pragma unroll
  for (int j = 0; j < 16; ++j) acc[j] = 0.f;
  for (int ci = 0; ci < C2; ++ci) {
    float u = sH[ci][lx];
#pragma unroll
    for (int j = 0; j < 16; ++j)
      acc[j] += u * sW[(dg * 16 + j) * 33 + ci];
  }
  int row = (n * H2 + y) * W2 + lx;
#pragma unroll
  for (int j = 0; j < 16; ++j)
    z[row * Dd + dg * 16 + j] = acc[j] + b[dg * 16 + j];
}

// ---------- VQ: argmin + loss ----------
__global__ __launch_bounds__(256) void k_vq(
    const float* __restrict__ z, const float* __restrict__ cbf,
    int* __restrict__ idx, float* __restrict__ lossA, int row0)
{
  __shared__ float c2s[Kc];
  int tid = threadIdx.x;
  for (int c = tid; c < Kc; c += 256) {
    float s = 0.f;
#pragma unroll
    for (int d = 0; d < Dd; ++d) { float v = cbf[c * Dd + d]; s += v * v; }
    c2s[c] = s;
  }
  __syncthreads();
  int r = blockIdx.x * 256 + tid;
  float4 zr[16];
  const float4* zp = (const float4*)(z + (size_t)r * Dd);
#pragma unroll
  for (int i = 0; i < 16; ++i) zr[i] = zp[i];
  float best = 1e30f; int bidx = 0;
  for (int c = 0; c < Kc; ++c) {
    const float* __restrict__ cr = cbf + c * Dd;
    float d0 = 0.f, d1 = 0.f, d2a = 0.f, d3 = 0.f;
#pragma unroll
    for (int i = 0; i < 16; ++i) {
      d0 += zr[i].x * cr[4 * i + 0];
      d1 += zr[i].y * cr[4 * i + 1];
      d2a += zr[i].z * cr[4 * i + 2];
      d3 += zr[i].w * cr[4 * i + 3];
    }
    float dot = (d0 + d1) + (d2a + d3);
    float dist = c2s[c] - 2.f * dot;
    if (dist < best) { best = dist; bidx = c; }
  }
  idx[row0 + r] = bidx;
  const float* cr = cbf + bidx * Dd;
  float ls = 0.f;
#pragma unroll
  for (int i = 0; i < 16; ++i) {
    float e0 = zr[i].x - cr[4 * i + 0];
    float e1 = zr[i].y - cr[4 * i + 1];
    float e2 = zr[i].z - cr[4 * i + 2];
    float e3 = zr[i].w - cr[4 * i + 3];
    ls += e0 * e0 + e1 * e1 + e2 * e2 + e3 * e3;
  }
#pragma unroll
  for (int off = 32; off > 0; off >>= 1) ls += __shfl_down(ls, off);
  if ((tid & 63) == 0) atomicAdd(lossA, ls);
}

__global__ void k_loss_final(const float* __restrict__ a, float* __restrict__ out)
{
  if (threadIdx.x == 0) {
    float l = a[0] / (float)(ROWS * Dd);
    out[0] = l;
    out[1] = l;
  }
}

// ---------- dec conv1 (1x1, 64->32, ReLU) ----------
__global__ __launch_bounds__(256) void k_dec1(
    const int* __restrict__ idx, const float* __restrict__ cbf,
    const float* __restrict__ w, const float* __restrict__ b,
    float* __restrict__ d1, int row0)
{
  int bid = blockIdx.x;
  int y = bid & 63, n = bid >> 6;
  __shared__ float sZ[64 * 65];
  __shared__ float sW[32 * 65];
  int tid = threadIdx.x;
  int base = row0 + (n * H2 + y) * W2;
  {
    int d = tid & 63, x0 = tid >> 6;
    for (int k = 0; k < 16; ++k) {
      int xx = x0 + 4 * k;
      int ci = idx[base + xx];
      sZ[xx * 65 + d] = cbf[ci * Dd + d];
    }
  }
  for (int i = tid; i < 32 * Dd; i += 256) {
    int co = i >> 6, d = i & 63;
    sW[co * 65 + d] = w[i];
  }
  __syncthreads();
  int lx = tid & 63, cg = tid >> 6;
  float acc[8];
#pragma unroll
  for (int j = 0; j < 8; ++j) acc[j] = 0.f;
  for (int d = 0; d < Dd; ++d) {
    float u = sZ[lx * 65 + d];
#pragma unroll
    for (int j = 0; j < 8; ++j)
      acc[j] += u * sW[(cg * 8 + j) * 65 + d];
  }
#pragma unroll
  for (int j = 0; j < 8; ++j) {
    int co = cg * 8 + j;
    float v = acc[j] + b[co];
    v = v > 0.f ? v : 0.f;
    d1[((n * C2 + co) * H2 + y) * W2 + lx] = v;
  }
}

// ---------- composed upsample2x+conv3x3 as 4-phase conv on low-res grid ----------
// Register-blocked per channel: only 9 input values live at a time (t9),
// each consumed COCH*4 times from registers. Interior-exact; border ring
// overwritten by k_upfix.
template <int Ci, int Hi, int Co, int COCH, bool RELU>
__global__ __launch_bounds__(256) void k_upconv2x(
    const float* __restrict__ I, const float* __restrict__ k2,
    const float* __restrict__ bias, float* __restrict__ O, int n0)
{
  constexpr int TT = Hi / 16, NCG = Co / COCH, Ho = 2 * Hi, Wo = 2 * Hi;
  int bid = blockIdx.x;
  int tx = bid % TT; bid /= TT;
  int ty = bid % TT; bid /= TT;
  int cg = bid % NCG; bid /= NCG;
  int n = bid;
  int Y0 = ty * 16, X0 = tx * 16;
  __shared__ float sI[4][18 * 19];
  int tid = threadIdx.x;
  int lx = tid & 15, ly = tid >> 4;
  float acc[COCH][4];
#pragma unroll
  for (int j = 0; j < COCH; ++j)
#pragma unroll
    for (int ph = 0; ph < 4; ++ph) acc[j][ph] = 0.f;
  const float* kbase = k2 + (size_t)cg * COCH * Ci * 36;
  for (int c0 = 0; c0 < Ci; c0 += 4) {
    __syncthreads();
    for (int i = tid; i < 4 * 18 * 18; i += 256) {
      int s = i / 324, r2 = i % 324;
      int rr = r2 / 18, cc = r2 % 18;
      int gy = Y0 - 1 + rr; gy = gy < 0 ? 0 : (gy > Hi - 1 ? Hi - 1 : gy);
      int gx = X0 - 1 + cc; gx = gx < 0 ? 0 : (gx > Hi - 1 ? Hi - 1 : gx);
      sI[s][rr * 19 + cc] = I[((size_t)n * Ci + c0 + s) * Hi * Hi + gy * Hi + gx];
    }
    __syncthreads();
#pragma unroll
    for (int s = 0; s < 4; ++s) {
      float t9[9];
#pragma unroll
      for (int dy = 0; dy < 3; ++dy)
#pragma unroll
        for (int dx = 0; dx < 3; ++dx)
          t9[dy * 3 + dx] = sI[s][(ly + dy) * 19 + lx + dx];
#pragma unroll
      for (int j = 0; j < COCH; ++j) {
        const float* kj = kbase + ((size_t)j * Ci + c0 + s) * 36;
#pragma unroll
        for (int ph = 0; ph < 4; ++ph)
#pragma unroll
          for (int tp = 0; tp < 9; ++tp)
            acc[j][ph] += t9[tp] * kj[ph * 9 + tp];
      }
    }
  }
  int oy = 2 * (Y0 + ly), ox = 2 * (X0 + lx);
#pragma unroll
  for (int j = 0; j < COCH; ++j) {
    int co = cg * COCH + j;
    float bv = bias[co];
#pragma unroll
    for (int py = 0; py < 2; ++py) {
      float2 v;
      v.x = acc[j][py * 2 + 0] + bv;
      v.y = acc[j][py * 2 + 1] + bv;
      if (RELU) { v.x = v.x > 0.f ? v.x : 0.f; v.y = v.y > 0.f ? v.y : 0.f; }
      size_t off = ((size_t)((n0 + n) * Co + co) * Ho + oy + py) * Wo + ox;
      *(float2*)&O[off] = v;
    }
  }
}

// ---------- exact direct computation of the output border ring ----------
template <int Ci, int Hi, int Co, int CG, bool RELU>
__global__ __launch_bounds__(256) void k_upfix(
    const float* __restrict__ I, const float* __restrict__ w,
    const float* __restrict__ bias, float* __restrict__ O, int CHn, int n0)
{
  constexpr int Ho = 2 * Hi, Wo = 2 * Hi;
  constexpr int RING = 2 * (Ho + Wo) - 4;
  constexpr int NCG = Co / CG;
  int gi = blockIdx.x * 256 + threadIdx.x;
  if (gi >= CHn * NCG * RING) return;
  int p = gi % RING;
  int cgrp = (gi / RING) % NCG;
  int n = gi / (RING * NCG);
  int u, v;
  if (p < Wo)            { u = 0;       v = p; }
  else if (p < 2 * Wo)   { u = Ho - 1;  v = p - Wo; }
  else { int q = p - 2 * Wo; u = 1 + (q >> 1); v = (q & 1) ? (Wo - 1) : 0; }
  float acc[CG];
#pragma unroll
  for (int j = 0; j < CG; ++j) acc[j] = 0.f;
  for (int ci = 0; ci < Ci; ++ci) {
    const float* Ip = I + ((size_t)n * Ci + ci) * Hi * Hi;
    float U[9];
#pragma unroll
    for (int dy = 0; dy < 3; ++dy)
#pragma unroll
      for (int dx = 0; dx < 3; ++dx) {
        int vy = u - 1 + dy, vx = v - 1 + dx;
        float val = 0.f;
        if (vy >= 0 && vy < Ho && vx >= 0 && vx < Wo) {
          int ky0, ky1, kx0, kx1; float ay0, ax0;
          if (vy & 1) { ky0 = vy >> 1; ky1 = ky0 + 1; ay0 = .75f; }
          else        { ky1 = vy >> 1; ky0 = ky1 - 1; ay0 = .25f; }
          if (vx & 1) { kx0 = vx >> 1; kx1 = kx0 + 1; ax0 = .75f; }
          else        { kx1 = vx >> 1; kx0 = kx1 - 1; ax0 = .25f; }
          ky0 = ky0 < 0 ? 0 : (ky0 > Hi - 1 ? Hi - 1 : ky0);
          ky1 = ky1 < 0 ? 0 : (ky1 > Hi - 1 ? Hi - 1 : ky1);
          kx0 = kx0 < 0 ? 0 : (kx0 > Hi - 1 ? Hi - 1 : kx0);
          kx1 = kx1 < 0 ? 0 : (kx1 > Hi - 1 ? Hi - 1 : kx1);
          float ay1 = 1.f - ay0, ax1 = 1.f - ax0;
          float r0 = ax0 * Ip[ky0 * Hi + kx0] + ax1 * Ip[ky0 * Hi + kx1];
          float r1 = ax0 * Ip[ky1 * Hi + kx0] + ax1 * Ip[ky1 * Hi + kx1];
          val = ay0 * r0 + ay1 * r1;
        }
        U[dy * 3 + dx] = val;
      }
#pragma unroll
    for (int j = 0; j < CG; ++j) {
      const float* wp = w + ((size_t)(cgrp * CG + j) * Ci + ci) * 9;
#pragma unroll
      for (int tp = 0; tp < 9; ++tp) acc[j] += U[tp] * wp[tp];
    }
  }
#pragma unroll
  for (int j = 0; j < CG; ++j) {
    int co = cgrp * CG + j;
    float val = acc[j] + bias[co];
    if (RELU) val = val > 0.f ? val : 0.f;
    O[((size_t)((n0 + n) * Co + co) * Ho + u) * Wo + v] = val;
  }
}

extern "C" void kernel_launch(void* const* d_in, const int* in_sizes, int n_in,
                              void* d_out, int out_size, void* d_ws, size_t ws_size,
                              hipStream_t stream)
{
  const float* x      = (const float*)d_in[0];
  const float* cb     = (const float*)d_in[1];
  const float* enc_w1 = (const float*)d_in[2];
  const float* enc_b1 = (const float*)d_in[3];
  const float* enc_w2 = (const float*)d_in[4];
  const float* enc_b2 = (const float*)d_in[5];
  const float* enc_w3 = (const float*)d_in[6];
  const float* enc_b3 = (const float*)d_in[7];
  const float* dec_w1 = (const float*)d_in[8];
  const float* dec_b1 = (const float*)d_in[9];
  const float* dec_w2 = (const float*)d_in[10];
  const float* dec_b2 = (const float*)d_in[11];
  const float* dec_w3 = (const float*)d_in[12];
  const float* dec_b3 = (const float*)d_in[13];

  float* ws = (float*)d_ws;
  float* lossA = ws;                      // 64
  int* idx = (int*)(lossA + 64);          // ROWS ints
  float* k2a = (float*)(idx + ROWS);      // 73728
  float* k2b = k2a + K2A_FLOATS;          // 6912
  float* chunkbuf = k2b + K2B_FLOATS + 64;

  int CH = 1;
  for (int c = 32; c >= 1; c >>= 1) {
    size_t need = ((size_t)FIX_FLOATS + (size_t)(H1_PER_N + Z_PER_N + H2_PER_N) * c) * 4;
    if (need <= ws_size) { CH = c; break; }
  }
  float* h1 = chunkbuf;                   // CH * 1,048,576  (reused as d2)
  float* z  = h1 + (size_t)H1_PER_N * CH; // CH * 262,144
  float* h2 = z + (size_t)Z_PER_N * CH;   // CH * 131,072    (reused as d1)

  k_zero<<<1, 64, 0, stream>>>(lossA);
  k_wtrans<<<(64 * 32 + 255) / 256, 256, 0, stream>>>(dec_w2, k2a, 64 * 32);
  k_wtrans<<<1, 256, 0, stream>>>(dec_w3, k2b, 3 * 64);

  float* out = (float*)d_out;

  for (int n0 = 0; n0 < Bn; n0 += CH) {
    int row0 = n0 * H2 * W2;
    k_conv1<<<CH * 128, 256, 0, stream>>>(x, enc_w1, enc_b1, h1, n0);
    k_conv2<<<CH * 16, 256, 0, stream>>>(h1, enc_w2, enc_b2, h2);
    k_conv3z<<<CH * 64, 256, 0, stream>>>(h2, enc_w3, enc_b3, z);
    k_vq<<<CH * 16, 256, 0, stream>>>(z, cb, idx, lossA, row0);
    k_dec1<<<CH * 64, 256, 0, stream>>>(idx, cb, dec_w1, dec_b1, h2, row0);
    // d1 (h2) -> d2 (h1): 32ch 64x64 -> 64ch 128x128, ReLU
    k_upconv2x<32, 64, 64, 8, true><<<CH * 8 * 4 * 4, 256, 0, stream>>>(
        h2, k2a, dec_b2, h1, 0);
    k_upfix<32, 64, 64, 16, true>
        <<<(CH * 4 * 508 + 255) / 256, 256, 0, stream>>>(
            h2, dec_w2, dec_b2, h1, CH, 0);
    // d2 (h1) -> recon: 64ch 128x128 -> 3ch 256x256, f32 out at offset 2
    k_upconv2x<64, 128, 3, 3, false><<<CH * 1 * 8 * 8, 256, 0, stream>>>(
        h1, k2b, dec_b3, out + 2, n0);
    k_upfix<64, 128, 3, 3, false>
        <<<(CH * 1 * 1020 + 255) / 256, 256, 0, stream>>>(
            h1, dec_w3, dec_b3, out + 2, CH, n0);
  }
  k_loss_final<<<1, 64, 0, stream>>>(lossA, out);
}

// Round 6
// 1904.658 us; speedup vs baseline: 1.1090x; 1.0795x over previous
//
#include <hip/hip_runtime.h>
#include <hip/hip_bf16.h>

static constexpr int Bn = 32;
static constexpr int Hin = 256, Win = 256;
static constexpr int C1 = 64, H1 = 128, W1 = 128;
static constexpr int C2 = 32, H2 = 64, W2 = 64;
static constexpr int Dd = 64;    // latent dim
static constexpr int Kc = 512;   // codebook entries
static constexpr int ROWS = Bn * H2 * W2;  // 131072

// ws layout (floats): lossA(64) | idx(131072 ints) | k2a(73728) | k2b(6912) | chunk
static constexpr int K2A_FLOATS = 64 * 32 * 36;  // 73728
static constexpr int K2B_FLOATS = 3 * 64 * 36;   // 6912
static constexpr int FIX_FLOATS = 64 + ROWS + K2A_FLOATS + K2B_FLOATS + 64;
static constexpr int H1_PER_N = C1 * H1 * W1;    // 1,048,576
static constexpr int Z_PER_N  = H2 * W2 * Dd;    // 262,144
static constexpr int H2_PER_N = C2 * H2 * W2;    // 131,072

__global__ void k_zero(float* p) { p[threadIdx.x] = 0.f; }

// ---------- upsample-conv weight compose: K'[py,px] = Ay^T W Ax ----------
__global__ __launch_bounds__(256) void k_wtrans(
    const float* __restrict__ w, float* __restrict__ k2, int N)
{
  int i = blockIdx.x * 256 + threadIdx.x;
  if (i >= N) return;
  float W[3][3];
#pragma unroll
  for (int ty = 0; ty < 3; ++ty)
#pragma unroll
    for (int tx = 0; tx < 3; ++tx) W[ty][tx] = w[i * 9 + ty * 3 + tx];
  const float A[2][3][3] = {
      {{.75f, .25f, 0.f}, {.25f, .75f, 0.f}, {0.f, .75f, .25f}},
      {{.25f, .75f, 0.f}, {0.f, .75f, .25f}, {0.f, .25f, .75f}}};
#pragma unroll
  for (int py = 0; py < 2; ++py)
#pragma unroll
    for (int px = 0; px < 2; ++px)
#pragma unroll
      for (int a = 0; a < 3; ++a)
#pragma unroll
        for (int b = 0; b < 3; ++b) {
          float v = 0.f;
#pragma unroll
          for (int ty = 0; ty < 3; ++ty)
#pragma unroll
            for (int tx = 0; tx < 3; ++tx)
              v += W[ty][tx] * A[py][ty][a] * A[px][tx][b];
          k2[(size_t)i * 36 + (py * 2 + px) * 9 + a * 3 + b] = v;
        }
}

// ---------- enc conv1: 3->64, 3x3, s2, p1, ReLU ----------
__global__ __launch_bounds__(256) void k_conv1(
    const float* __restrict__ x, const float* __restrict__ w,
    const float* __restrict__ b, float* __restrict__ h1, int n0)
{
  int bid = blockIdx.x;
  int xt = bid & 1, yt = (bid >> 1) & 15, cc = (bid >> 5) & 3, n = bid >> 7;
  int X0 = xt * 64, Y0 = yt * 8, co0 = cc * 16;
  __shared__ float sIn[3][17][130];
  int tid = threadIdx.x;
  for (int i = tid; i < 3 * 17 * 130; i += 256) {
    int ci = i / (17 * 130);
    int rr = (i / 130) % 17;
    int ccx = i % 130;
    int gy = 2 * Y0 - 1 + rr, gx = 2 * X0 - 1 + ccx;
    float v = 0.f;
    if (gy >= 0 && gy < Hin && gx >= 0 && gx < Win)
      v = x[(((size_t)(n0 + n) * 3 + ci) * Hin + gy) * Win + gx];
    sIn[ci][rr][ccx] = v;
  }
  __syncthreads();
  int lx = tid & 63, ys = tid >> 6;
  float acc[16][2];
#pragma unroll
  for (int c = 0; c < 16; ++c) { acc[c][0] = 0.f; acc[c][1] = 0.f; }
#pragma unroll
  for (int ci = 0; ci < 3; ++ci)
#pragma unroll
    for (int ky = 0; ky < 3; ++ky)
#pragma unroll
      for (int kx = 0; kx < 3; ++kx) {
        float u0 = sIn[ci][2 * ys + ky][2 * lx + kx];
        float u1 = sIn[ci][2 * ys + 8 + ky][2 * lx + kx];
#pragma unroll
        for (int c = 0; c < 16; ++c) {
          float wv = w[((co0 + c) * 3 + ci) * 9 + ky * 3 + kx];
          acc[c][0] += u0 * wv;
          acc[c][1] += u1 * wv;
        }
      }
#pragma unroll
  for (int c = 0; c < 16; ++c) {
    float bv = b[co0 + c];
    float v0 = acc[c][0] + bv; v0 = v0 > 0.f ? v0 : 0.f;
    float v1 = acc[c][1] + bv; v1 = v1 > 0.f ? v1 : 0.f;
    h1[((n * C1 + co0 + c) * H1 + Y0 + ys) * W1 + X0 + lx] = v0;
    h1[((n * C1 + co0 + c) * H1 + Y0 + ys + 4) * W1 + X0 + lx] = v1;
  }
}

// ---------- enc conv2: 64->32, 3x3, s2, p1, ReLU ----------
__global__ __launch_bounds__(256) void k_conv2(
    const float* __restrict__ h1, const float* __restrict__ w,
    const float* __restrict__ b, float* __restrict__ h2)
{
  int bid = blockIdx.x;
  int yt = bid & 7, cc = (bid >> 3) & 1, n = bid >> 4;
  int Y0 = yt * 8, co0 = cc * 16;
  __shared__ float sIn[4][17][130];
  int tid = threadIdx.x;
  int lx = tid & 63, ys = tid >> 6;
  float acc[16][2];
#pragma unroll
  for (int c = 0; c < 16; ++c) { acc[c][0] = 0.f; acc[c][1] = 0.f; }
  for (int cb0 = 0; cb0 < C1; cb0 += 4) {
    __syncthreads();
    for (int i = tid; i < 4 * 17 * 130; i += 256) {
      int ci = i / (17 * 130);
      int rr = (i / 130) % 17;
      int ccx = i % 130;
      int gy = 2 * Y0 - 1 + rr, gx = -1 + ccx;
      float v = 0.f;
      if (gy >= 0 && gy < H1 && gx >= 0 && gx < W1)
        v = h1[((n * C1 + cb0 + ci) * H1 + gy) * W1 + gx];
      sIn[ci][rr][ccx] = v;
    }
    __syncthreads();
#pragma unroll
    for (int ci = 0; ci < 4; ++ci)
#pragma unroll
      for (int ky = 0; ky < 3; ++ky)
#pragma unroll
        for (int kx = 0; kx < 3; ++kx) {
          float u0 = sIn[ci][2 * ys + ky][2 * lx + kx];
          float u1 = sIn[ci][2 * ys + 8 + ky][2 * lx + kx];
#pragma unroll
          for (int c = 0; c < 16; ++c) {
            float wv = w[((co0 + c) * C1 + cb0 + ci) * 9 + ky * 3 + kx];
            acc[c][0] += u0 * wv;
            acc[c][1] += u1 * wv;
          }
        }
  }
#pragma unroll
  for (int c = 0; c < 16; ++c) {
    float bv = b[co0 + c];
    float v0 = acc[c][0] + bv; v0 = v0 > 0.f ? v0 : 0.f;
    float v1 = acc[c][1] + bv; v1 = v1 > 0.f ? v1 : 0.f;
    h2[((n * C2 + co0 + c) * H2 + Y0 + ys) * W2 + lx] = v0;
    h2[((n * C2 + co0 + c) * H2 + Y0 + ys + 4) * W2 + lx] = v1;
  }
}

// ---------- enc conv3 (1x1, 32->64) -> z in [row][64] ----------
__global__ __launch_bounds__(256) void k_conv3z(
    const float* __restrict__ h2, const float* __restrict__ w,
    const float* __restrict__ b, float* __restrict__ z)
{
  int bid = blockIdx.x;
  int y = bid & 63, n = bid >> 6;
  __shared__ float sH[C2][64];
  __shared__ float sW[Dd * 33];
  int tid = threadIdx.x;
  for (int i = tid; i < C2 * 64; i += 256) {
    int ci = i >> 6, xx = i & 63;
    sH[ci][xx] = h2[((n * C2 + ci) * H2 + y) * W2 + xx];
  }
  for (int i = tid; i < Dd * C2; i += 256) {
    int d = i >> 5, ci = i & 31;
    sW[d * 33 + ci] = w[i];
  }
  __syncthreads();
  int dg = tid & 3, lx = tid >> 2;
  float acc[16];
#pragma unroll
  for (int j = 0; j < 16; ++j) acc[j] = 0.f;
  for (int ci = 0; ci < C2; ++ci) {
    float u = sH[ci][lx];
#pragma unroll
    for (int j = 0; j < 16; ++j)
      acc[j] += u * sW[(dg * 16 + j) * 33 + ci];
  }
  int row = (n * H2 + y) * W2 + lx;
#pragma unroll
  for (int j = 0; j < 16; ++j)
    z[row * Dd + dg * 16 + j] = acc[j] + b[dg * 16 + j];
}

// ---------- VQ: argmin + loss ----------
__global__ __launch_bounds__(256) void k_vq(
    const float* __restrict__ z, const float* __restrict__ cbf,
    int* __restrict__ idx, float* __restrict__ lossA, int row0)
{
  __shared__ float c2s[Kc];
  int tid = threadIdx.x;
  for (int c = tid; c < Kc; c += 256) {
    float s = 0.f;
#pragma unroll
    for (int d = 0; d < Dd; ++d) { float v = cbf[c * Dd + d]; s += v * v; }
    c2s[c] = s;
  }
  __syncthreads();
  int r = blockIdx.x * 256 + tid;
  float4 zr[16];
  const float4* zp = (const float4*)(z + (size_t)r * Dd);
#pragma unroll
  for (int i = 0; i < 16; ++i) zr[i] = zp[i];
  float best = 1e30f; int bidx = 0;
  for (int c = 0; c < Kc; ++c) {
    const float* __restrict__ cr = cbf + c * Dd;
    float d0 = 0.f, d1 = 0.f, d2a = 0.f, d3 = 0.f;
#pragma unroll
    for (int i = 0; i < 16; ++i) {
      d0 += zr[i].x * cr[4 * i + 0];
      d1 += zr[i].y * cr[4 * i + 1];
      d2a += zr[i].z * cr[4 * i + 2];
      d3 += zr[i].w * cr[4 * i + 3];
    }
    float dot = (d0 + d1) + (d2a + d3);
    float dist = c2s[c] - 2.f * dot;
    if (dist < best) { best = dist; bidx = c; }
  }
  idx[row0 + r] = bidx;
  const float* cr = cbf + bidx * Dd;
  float ls = 0.f;
#pragma unroll
  for (int i = 0; i < 16; ++i) {
    float e0 = zr[i].x - cr[4 * i + 0];
    float e1 = zr[i].y - cr[4 * i + 1];
    float e2 = zr[i].z - cr[4 * i + 2];
    float e3 = zr[i].w - cr[4 * i + 3];
    ls += e0 * e0 + e1 * e1 + e2 * e2 + e3 * e3;
  }
#pragma unroll
  for (int off = 32; off > 0; off >>= 1) ls += __shfl_down(ls, off);
  if ((tid & 63) == 0) atomicAdd(lossA, ls);
}

__global__ void k_loss_final(const float* __restrict__ a, float* __restrict__ out)
{
  if (threadIdx.x == 0) {
    float l = a[0] / (float)(ROWS * Dd);
    out[0] = l;
    out[1] = l;
  }
}

// ---------- dec conv1 (1x1, 64->32, ReLU) ----------
__global__ __launch_bounds__(256) void k_dec1(
    const int* __restrict__ idx, const float* __restrict__ cbf,
    const float* __restrict__ w, const float* __restrict__ b,
    float* __restrict__ d1, int row0)
{
  int bid = blockIdx.x;
  int y = bid & 63, n = bid >> 6;
  __shared__ float sZ[64 * 65];
  __shared__ float sW[32 * 65];
  int tid = threadIdx.x;
  int base = row0 + (n * H2 + y) * W2;
  {
    int d = tid & 63, x0 = tid >> 6;
    for (int k = 0; k < 16; ++k) {
      int xx = x0 + 4 * k;
      int ci = idx[base + xx];
      sZ[xx * 65 + d] = cbf[ci * Dd + d];
    }
  }
  for (int i = tid; i < 32 * Dd; i += 256) {
    int co = i >> 6, d = i & 63;
    sW[co * 65 + d] = w[i];
  }
  __syncthreads();
  int lx = tid & 63, cg = tid >> 6;
  float acc[8];
#pragma unroll
  for (int j = 0; j < 8; ++j) acc[j] = 0.f;
  for (int d = 0; d < Dd; ++d) {
    float u = sZ[lx * 65 + d];
#pragma unroll
    for (int j = 0; j < 8; ++j)
      acc[j] += u * sW[(cg * 8 + j) * 65 + d];
  }
#pragma unroll
  for (int j = 0; j < 8; ++j) {
    int co = cg * 8 + j;
    float v = acc[j] + b[co];
    v = v > 0.f ? v : 0.f;
    d1[((n * C2 + co) * H2 + y) * W2 + lx] = v;
  }
}

// ---------- composed upsample2x+conv3x3 as 4-phase conv on low-res grid ----------
// v3: each thread owns a 2x2 low-res pixel block (4x4 hi-res) x COCH channels.
// Per (j,a,b) tap: 4 scalar weight loads feed 16 INDEPENDENT FMAs (1:4 scalar
// ratio, no same-acc dependence chains). Interior-exact; border ring
// overwritten by k_upfix.
template <int Ci, int Hi, int Co, int COCH, bool RELU>
__global__ __launch_bounds__(256) void k_upconv2x(
    const float* __restrict__ I, const float* __restrict__ k2,
    const float* __restrict__ bias, float* __restrict__ O, int n0)
{
  constexpr int TT = Hi / 32, NCG = Co / COCH, Ho = 2 * Hi, Wo = 2 * Hi;
  int bid = blockIdx.x;
  int tx = bid % TT; bid /= TT;
  int ty = bid % TT; bid /= TT;
  int cg = bid % NCG; bid /= NCG;
  int n = bid;
  int Y0 = ty * 32, X0 = tx * 32;
  __shared__ float sI[4][34 * 35];
  int tid = threadIdx.x;
  int lx = tid & 15, ly = tid >> 4;  // 16x16 threads, each 2x2 low-res px
  float4 acc[COCH][2][2];            // [j][pyy][py] over (pxx,px)
#pragma unroll
  for (int j = 0; j < COCH; ++j)
#pragma unroll
    for (int a = 0; a < 2; ++a)
#pragma unroll
      for (int b = 0; b < 2; ++b) acc[j][a][b] = make_float4(0.f, 0.f, 0.f, 0.f);
  const float* kbase = k2 + (size_t)cg * COCH * Ci * 36;
  for (int c0 = 0; c0 < Ci; c0 += 4) {
    __syncthreads();
    for (int i = tid; i < 4 * 34 * 34; i += 256) {
      int s = i / 1156, r2 = i % 1156;
      int rr = r2 / 34, cc2 = r2 % 34;
      int gy = Y0 - 1 + rr; gy = gy < 0 ? 0 : (gy > Hi - 1 ? Hi - 1 : gy);
      int gx = X0 - 1 + cc2; gx = gx < 0 ? 0 : (gx > Hi - 1 ? Hi - 1 : gx);
      sI[s][rr * 35 + cc2] = I[((size_t)n * Ci + c0 + s) * Hi * Hi + gy * Hi + gx];
    }
    __syncthreads();
#pragma unroll
    for (int s = 0; s < 4; ++s) {
      float t[4][4];
#pragma unroll
      for (int r = 0; r < 4; ++r)
#pragma unroll
        for (int c = 0; c < 4; ++c)
          t[r][c] = sI[s][(2 * ly + r) * 35 + 2 * lx + c];
#pragma unroll
      for (int j = 0; j < COCH; ++j) {
        const float* kj = kbase + ((size_t)j * Ci + c0 + s) * 36;
#pragma unroll
        for (int a = 0; a < 3; ++a)
#pragma unroll
          for (int b = 0; b < 3; ++b) {
            float w00 = kj[a * 3 + b];
            float w01 = kj[9 + a * 3 + b];
            float w10 = kj[18 + a * 3 + b];
            float w11 = kj[27 + a * 3 + b];
#pragma unroll
            for (int pyy = 0; pyy < 2; ++pyy) {
              float i0 = t[pyy + a][b];
              float i1 = t[pyy + a][b + 1];
              acc[j][pyy][0].x += i0 * w00;
              acc[j][pyy][0].y += i0 * w01;
              acc[j][pyy][0].z += i1 * w00;
              acc[j][pyy][0].w += i1 * w01;
              acc[j][pyy][1].x += i0 * w10;
              acc[j][pyy][1].y += i0 * w11;
              acc[j][pyy][1].z += i1 * w10;
              acc[j][pyy][1].w += i1 * w11;
            }
          }
      }
    }
  }
  int ox = 2 * X0 + 4 * lx;
#pragma unroll
  for (int j = 0; j < COCH; ++j) {
    int co = cg * COCH + j;
    float bv = bias[co];
#pragma unroll
    for (int pyy = 0; pyy < 2; ++pyy) {
      int oy0 = 2 * (Y0 + 2 * ly + pyy);
#pragma unroll
      for (int py = 0; py < 2; ++py) {
        float4 v = acc[j][pyy][py];
        v.x += bv; v.y += bv; v.z += bv; v.w += bv;
        if (RELU) {
          v.x = v.x > 0.f ? v.x : 0.f;
          v.y = v.y > 0.f ? v.y : 0.f;
          v.z = v.z > 0.f ? v.z : 0.f;
          v.w = v.w > 0.f ? v.w : 0.f;
        }
        size_t off = (((size_t)(n0 + n) * Co + co) * Ho + oy0 + py) * Wo + ox;
        *(float4*)&O[off] = v;
      }
    }
  }
}

// ---------- exact direct computation of the output border ring ----------
template <int Ci, int Hi, int Co, int CG, bool RELU>
__global__ __launch_bounds__(256) void k_upfix(
    const float* __restrict__ I, const float* __restrict__ w,
    const float* __restrict__ bias, float* __restrict__ O, int CHn, int n0)
{
  constexpr int Ho = 2 * Hi, Wo = 2 * Hi;
  constexpr int RING = 2 * (Ho + Wo) - 4;
  constexpr int NCG = Co / CG;
  int gi = blockIdx.x * 256 + threadIdx.x;
  if (gi >= CHn * NCG * RING) return;
  int p = gi % RING;
  int cgrp = (gi / RING) % NCG;
  int n = gi / (RING * NCG);
  int u, v;
  if (p < Wo)            { u = 0;       v = p; }
  else if (p < 2 * Wo)   { u = Ho - 1;  v = p - Wo; }
  else { int q = p - 2 * Wo; u = 1 + (q >> 1); v = (q & 1) ? (Wo - 1) : 0; }
  float acc[CG];
#pragma unroll
  for (int j = 0; j < CG; ++j) acc[j] = 0.f;
  for (int ci = 0; ci < Ci; ++ci) {
    const float* Ip = I + ((size_t)n * Ci + ci) * Hi * Hi;
    float U[9];
#pragma unroll
    for (int dy = 0; dy < 3; ++dy)
#pragma unroll
      for (int dx = 0; dx < 3; ++dx) {
        int vy = u - 1 + dy, vx = v - 1 + dx;
        float val = 0.f;
        if (vy >= 0 && vy < Ho && vx >= 0 && vx < Wo) {
          int ky0, ky1, kx0, kx1; float ay0, ax0;
          if (vy & 1) { ky0 = vy >> 1; ky1 = ky0 + 1; ay0 = .75f; }
          else        { ky1 = vy >> 1; ky0 = ky1 - 1; ay0 = .25f; }
          if (vx & 1) { kx0 = vx >> 1; kx1 = kx0 + 1; ax0 = .75f; }
          else        { kx1 = vx >> 1; kx0 = kx1 - 1; ax0 = .25f; }
          ky0 = ky0 < 0 ? 0 : (ky0 > Hi - 1 ? Hi - 1 : ky0);
          ky1 = ky1 < 0 ? 0 : (ky1 > Hi - 1 ? Hi - 1 : ky1);
          kx0 = kx0 < 0 ? 0 : (kx0 > Hi - 1 ? Hi - 1 : kx0);
          kx1 = kx1 < 0 ? 0 : (kx1 > Hi - 1 ? Hi - 1 : kx1);
          float ay1 = 1.f - ay0, ax1 = 1.f - ax0;
          float r0 = ax0 * Ip[ky0 * Hi + kx0] + ax1 * Ip[ky0 * Hi + kx1];
          float r1 = ax0 * Ip[ky1 * Hi + kx0] + ax1 * Ip[ky1 * Hi + kx1];
          val = ay0 * r0 + ay1 * r1;
        }
        U[dy * 3 + dx] = val;
      }
#pragma unroll
    for (int j = 0; j < CG; ++j) {
      const float* wp = w + ((size_t)(cgrp * CG + j) * Ci + ci) * 9;
#pragma unroll
      for (int tp = 0; tp < 9; ++tp) acc[j] += U[tp] * wp[tp];
    }
  }
#pragma unroll
  for (int j = 0; j < CG; ++j) {
    int co = cgrp * CG + j;
    float val = acc[j] + bias[co];
    if (RELU) val = val > 0.f ? val : 0.f;
    O[((size_t)((n0 + n) * Co + co) * Ho + u) * Wo + v] = val;
  }
}

extern "C" void kernel_launch(void* const* d_in, const int* in_sizes, int n_in,
                              void* d_out, int out_size, void* d_ws, size_t ws_size,
                              hipStream_t stream)
{
  const float* x      = (const float*)d_in[0];
  const float* cb     = (const float*)d_in[1];
  const float* enc_w1 = (const float*)d_in[2];
  const float* enc_b1 = (const float*)d_in[3];
  const float* enc_w2 = (const float*)d_in[4];
  const float* enc_b2 = (const float*)d_in[5];
  const float* enc_w3 = (const float*)d_in[6];
  const float* enc_b3 = (const float*)d_in[7];
  const float* dec_w1 = (const float*)d_in[8];
  const float* dec_b1 = (const float*)d_in[9];
  const float* dec_w2 = (const float*)d_in[10];
  const float* dec_b2 = (const float*)d_in[11];
  const float* dec_w3 = (const float*)d_in[12];
  const float* dec_b3 = (const float*)d_in[13];

  float* ws = (float*)d_ws;
  float* lossA = ws;                      // 64
  int* idx = (int*)(lossA + 64);          // ROWS ints
  float* k2a = (float*)(idx + ROWS);      // 73728
  float* k2b = k2a + K2A_FLOATS;          // 6912
  float* chunkbuf = k2b + K2B_FLOATS + 64;

  int CH = 1;
  for (int c = 32; c >= 1; c >>= 1) {
    size_t need = ((size_t)FIX_FLOATS + (size_t)(H1_PER_N + Z_PER_N + H2_PER_N) * c) * 4;
    if (need <= ws_size) { CH = c; break; }
  }
  float* h1 = chunkbuf;                   // CH * 1,048,576  (reused as d2)
  float* z  = h1 + (size_t)H1_PER_N * CH; // CH * 262,144
  float* h2 = z + (size_t)Z_PER_N * CH;   // CH * 131,072    (reused as d1)

  k_zero<<<1, 64, 0, stream>>>(lossA);
  k_wtrans<<<(64 * 32 + 255) / 256, 256, 0, stream>>>(dec_w2, k2a, 64 * 32);
  k_wtrans<<<1, 256, 0, stream>>>(dec_w3, k2b, 3 * 64);

  float* out = (float*)d_out;

  for (int n0 = 0; n0 < Bn; n0 += CH) {
    int row0 = n0 * H2 * W2;
    k_conv1<<<CH * 128, 256, 0, stream>>>(x, enc_w1, enc_b1, h1, n0);
    k_conv2<<<CH * 16, 256, 0, stream>>>(h1, enc_w2, enc_b2, h2);
    k_conv3z<<<CH * 64, 256, 0, stream>>>(h2, enc_w3, enc_b3, z);
    k_vq<<<CH * 16, 256, 0, stream>>>(z, cb, idx, lossA, row0);
    k_dec1<<<CH * 64, 256, 0, stream>>>(idx, cb, dec_w1, dec_b1, h2, row0);
    // d1 (h2) -> d2 (h1): 32ch 64x64 -> 64ch 128x128, ReLU
    // grid: n x cg(16) x ty(2) x tx(2)
    k_upconv2x<32, 64, 64, 4, true><<<CH * 16 * 2 * 2, 256, 0, stream>>>(
        h2, k2a, dec_b2, h1, 0);
    k_upfix<32, 64, 64, 16, true>
        <<<(CH * 4 * 508 + 255) / 256, 256, 0, stream>>>(
            h2, dec_w2, dec_b2, h1, CH, 0);
    // d2 (h1) -> recon: 64ch 128x128 -> 3ch 256x256, f32 out at offset 2
    // grid: n x cg(1) x ty(4) x tx(4)
    k_upconv2x<64, 128, 3, 3, false><<<CH * 1 * 4 * 4, 256, 0, stream>>>(
        h1, k2b, dec_b3, out + 2, n0);
    k_upfix<64, 128, 3, 3, false>
        <<<(CH * 1 * 1020 + 255) / 256, 256, 0, stream>>>(
            h1, dec_w3, dec_b3, out + 2, CH, n0);
  }
  k_loss_final<<<1, 64, 0, stream>>>(lossA, out);
}

// Round 7
// 1729.012 us; speedup vs baseline: 1.2217x; 1.1016x over previous
//
#include <hip/hip_runtime.h>
#include <hip/hip_bf16.h>

static constexpr int Bn = 32;
static constexpr int Hin = 256, Win = 256;
static constexpr int C1 = 64, H1 = 128, W1 = 128;
static constexpr int C2 = 32, H2 = 64, W2 = 64;
static constexpr int Dd = 64;    // latent dim
static constexpr int Kc = 512;   // codebook entries
static constexpr int ROWS = Bn * H2 * W2;  // 131072

// ws layout (floats): lossA(64) | idx(ROWS int) | pk(ROWS ull) | k2a | k2b | chunk
static constexpr int K2A_FLOATS = 64 * 32 * 36;  // 73728
static constexpr int K2B_FLOATS = 3 * 64 * 36;   // 6912
static constexpr int FIX_FLOATS = 64 + ROWS + 2 * ROWS + K2A_FLOATS + K2B_FLOATS + 64;
static constexpr int H1_PER_N = C1 * H1 * W1;    // 1,048,576
static constexpr int Z_PER_N  = H2 * W2 * Dd;    // 262,144
static constexpr int H2_PER_N = C2 * H2 * W2;    // 131,072

// ---------- init: zero loss accum, preset packed argmin keys ----------
__global__ __launch_bounds__(256) void k_init(
    float* __restrict__ lossA, unsigned long long* __restrict__ pk)
{
  int i = blockIdx.x * 256 + threadIdx.x;
  if (i < 64) lossA[i] = 0.f;
  pk[i] = 0xFFFFFFFFFFFFFFFFull;
}

// ---------- upsample-conv weight compose: K'[py,px] = Ay^T W Ax ----------
__global__ __launch_bounds__(256) void k_wtrans(
    const float* __restrict__ w, float* __restrict__ k2, int N)
{
  int i = blockIdx.x * 256 + threadIdx.x;
  if (i >= N) return;
  float W[3][3];
#pragma unroll
  for (int ty = 0; ty < 3; ++ty)
#pragma unroll
    for (int tx = 0; tx < 3; ++tx) W[ty][tx] = w[i * 9 + ty * 3 + tx];
  const float A[2][3][3] = {
      {{.75f, .25f, 0.f}, {.25f, .75f, 0.f}, {0.f, .75f, .25f}},
      {{.25f, .75f, 0.f}, {0.f, .75f, .25f}, {0.f, .25f, .75f}}};
#pragma unroll
  for (int py = 0; py < 2; ++py)
#pragma unroll
    for (int px = 0; px < 2; ++px)
#pragma unroll
      for (int a = 0; a < 3; ++a)
#pragma unroll
        for (int b = 0; b < 3; ++b) {
          float v = 0.f;
#pragma unroll
          for (int ty = 0; ty < 3; ++ty)
#pragma unroll
            for (int tx = 0; tx < 3; ++tx)
              v += W[ty][tx] * A[py][ty][a] * A[px][tx][b];
          k2[(size_t)i * 36 + (py * 2 + px) * 9 + a * 3 + b] = v;
        }
}

// ---------- enc conv1: 3->64, 3x3, s2, p1, ReLU ----------
__global__ __launch_bounds__(256) void k_conv1(
    const float* __restrict__ x, const float* __restrict__ w,
    const float* __restrict__ b, float* __restrict__ h1, int n0)
{
  int bid = blockIdx.x;
  int xt = bid & 1, yt = (bid >> 1) & 15, cc = (bid >> 5) & 3, n = bid >> 7;
  int X0 = xt * 64, Y0 = yt * 8, co0 = cc * 16;
  __shared__ float sIn[3][17][130];
  int tid = threadIdx.x;
  for (int i = tid; i < 3 * 17 * 130; i += 256) {
    int ci = i / (17 * 130);
    int rr = (i / 130) % 17;
    int ccx = i % 130;
    int gy = 2 * Y0 - 1 + rr, gx = 2 * X0 - 1 + ccx;
    float v = 0.f;
    if (gy >= 0 && gy < Hin && gx >= 0 && gx < Win)
      v = x[(((size_t)(n0 + n) * 3 + ci) * Hin + gy) * Win + gx];
    sIn[ci][rr][ccx] = v;
  }
  __syncthreads();
  int lx = tid & 63, ys = tid >> 6;
  float acc[16][2];
#pragma unroll
  for (int c = 0; c < 16; ++c) { acc[c][0] = 0.f; acc[c][1] = 0.f; }
#pragma unroll
  for (int ci = 0; ci < 3; ++ci)
#pragma unroll
    for (int ky = 0; ky < 3; ++ky)
#pragma unroll
      for (int kx = 0; kx < 3; ++kx) {
        float u0 = sIn[ci][2 * ys + ky][2 * lx + kx];
        float u1 = sIn[ci][2 * ys + 8 + ky][2 * lx + kx];
#pragma unroll
        for (int c = 0; c < 16; ++c) {
          float wv = w[((co0 + c) * 3 + ci) * 9 + ky * 3 + kx];
          acc[c][0] += u0 * wv;
          acc[c][1] += u1 * wv;
        }
      }
#pragma unroll
  for (int c = 0; c < 16; ++c) {
    float bv = b[co0 + c];
    float v0 = acc[c][0] + bv; v0 = v0 > 0.f ? v0 : 0.f;
    float v1 = acc[c][1] + bv; v1 = v1 > 0.f ? v1 : 0.f;
    h1[((n * C1 + co0 + c) * H1 + Y0 + ys) * W1 + X0 + lx] = v0;
    h1[((n * C1 + co0 + c) * H1 + Y0 + ys + 4) * W1 + X0 + lx] = v1;
  }
}

// ---------- enc conv2: 64->32, 3x3, s2, p1, ReLU ----------
__global__ __launch_bounds__(256) void k_conv2(
    const float* __restrict__ h1, const float* __restrict__ w,
    const float* __restrict__ b, float* __restrict__ h2)
{
  int bid = blockIdx.x;
  int yt = bid & 7, cc = (bid >> 3) & 1, n = bid >> 4;
  int Y0 = yt * 8, co0 = cc * 16;
  __shared__ float sIn[4][17][130];
  int tid = threadIdx.x;
  int lx = tid & 63, ys = tid >> 6;
  float acc[16][2];
#pragma unroll
  for (int c = 0; c < 16; ++c) { acc[c][0] = 0.f; acc[c][1] = 0.f; }
  for (int cb0 = 0; cb0 < C1; cb0 += 4) {
    __syncthreads();
    for (int i = tid; i < 4 * 17 * 130; i += 256) {
      int ci = i / (17 * 130);
      int rr = (i / 130) % 17;
      int ccx = i % 130;
      int gy = 2 * Y0 - 1 + rr, gx = -1 + ccx;
      float v = 0.f;
      if (gy >= 0 && gy < H1 && gx >= 0 && gx < W1)
        v = h1[((n * C1 + cb0 + ci) * H1 + gy) * W1 + gx];
      sIn[ci][rr][ccx] = v;
    }
    __syncthreads();
#pragma unroll
    for (int ci = 0; ci < 4; ++ci)
#pragma unroll
      for (int ky = 0; ky < 3; ++ky)
#pragma unroll
        for (int kx = 0; kx < 3; ++kx) {
          float u0 = sIn[ci][2 * ys + ky][2 * lx + kx];
          float u1 = sIn[ci][2 * ys + 8 + ky][2 * lx + kx];
#pragma unroll
          for (int c = 0; c < 16; ++c) {
            float wv = w[((co0 + c) * C1 + cb0 + ci) * 9 + ky * 3 + kx];
            acc[c][0] += u0 * wv;
            acc[c][1] += u1 * wv;
          }
        }
  }
#pragma unroll
  for (int c = 0; c < 16; ++c) {
    float bv = b[co0 + c];
    float v0 = acc[c][0] + bv; v0 = v0 > 0.f ? v0 : 0.f;
    float v1 = acc[c][1] + bv; v1 = v1 > 0.f ? v1 : 0.f;
    h2[((n * C2 + co0 + c) * H2 + Y0 + ys) * W2 + lx] = v0;
    h2[((n * C2 + co0 + c) * H2 + Y0 + ys + 4) * W2 + lx] = v1;
  }
}

// ---------- enc conv3 (1x1, 32->64) -> z in [row][64] ----------
__global__ __launch_bounds__(256) void k_conv3z(
    const float* __restrict__ h2, const float* __restrict__ w,
    const float* __restrict__ b, float* __restrict__ z)
{
  int bid = blockIdx.x;
  int y = bid & 63, n = bid >> 6;
  __shared__ float sH[C2][64];
  __shared__ float sW[Dd * 33];
  int tid = threadIdx.x;
  for (int i = tid; i < C2 * 64; i += 256) {
    int ci = i >> 6, xx = i & 63;
    sH[ci][xx] = h2[((n * C2 + ci) * H2 + y) * W2 + xx];
  }
  for (int i = tid; i < Dd * C2; i += 256) {
    int d = i >> 5, ci = i & 31;
    sW[d * 33 + ci] = w[i];
  }
  __syncthreads();
  int dg = tid & 3, lx = tid >> 2;
  float acc[16];
#pragma unroll
  for (int j = 0; j < 16; ++j) acc[j] = 0.f;
  for (int ci = 0; ci < C2; ++ci) {
    float u = sH[ci][lx];
#pragma unroll
    for (int j = 0; j < 16; ++j)
      acc[j] += u * sW[(dg * 16 + j) * 33 + ci];
  }
  int row = (n * H2 + y) * W2 + lx;
#pragma unroll
  for (int j = 0; j < 16; ++j)
    z[row * Dd + dg * 16 + j] = acc[j] + b[dg * 16 + j];
}

// ---------- VQ main: 4-way codebook split, packed atomicMin argmin ----------
// blockIdx = rb*4 + sp: rb = row block (256 rows), sp = codebook quarter.
// dist values identical to a sequential scan; tie-break: smaller idx wins
// (np.argmin first-occurrence semantics) via idx in low bits of the key.
__global__ __launch_bounds__(256) void k_vq(
    const float* __restrict__ z, const float* __restrict__ cbf,
    unsigned long long* __restrict__ pk, int row0)
{
  __shared__ float c2s[128];
  int bid = blockIdx.x;
  int sp = bid & 3, rb = bid >> 2;
  int c0 = sp * 128;
  int tid = threadIdx.x;
  if (tid < 128) {
    const float* cr = cbf + (size_t)(c0 + tid) * Dd;
    float s = 0.f;
#pragma unroll
    for (int d = 0; d < Dd; ++d) { float v = cr[d]; s += v * v; }
    c2s[tid] = s;
  }
  __syncthreads();
  int r = rb * 256 + tid;  // chunk-local row
  float4 zr[16];
  const float4* zp = (const float4*)(z + (size_t)r * Dd);
#pragma unroll
  for (int i = 0; i < 16; ++i) zr[i] = zp[i];
  float best = 1e30f; int bidx = c0;
  for (int c = 0; c < 128; ++c) {
    const float* __restrict__ cr = cbf + (size_t)(c0 + c) * Dd;
    float d0 = 0.f, d1 = 0.f, d2a = 0.f, d3 = 0.f;
#pragma unroll
    for (int i = 0; i < 16; ++i) {
      d0 += zr[i].x * cr[4 * i + 0];
      d1 += zr[i].y * cr[4 * i + 1];
      d2a += zr[i].z * cr[4 * i + 2];
      d3 += zr[i].w * cr[4 * i + 3];
    }
    float dot = (d0 + d1) + (d2a + d3);
    float dist = c2s[c] - 2.f * dot;
    if (dist < best) { best = dist; bidx = c0 + c; }
  }
  unsigned int u = __float_as_uint(best);
  unsigned int key32 = (u & 0x80000000u) ? ~u : (u | 0x80000000u);
  unsigned long long key =
      ((unsigned long long)key32 << 32) | (unsigned int)bidx;
  atomicMin(&pk[row0 + r], key);
}

// ---------- VQ merge: extract idx, accumulate loss ----------
__global__ __launch_bounds__(256) void k_vqfin(
    const float* __restrict__ z, const float* __restrict__ cbf,
    const unsigned long long* __restrict__ pk, int* __restrict__ idx,
    float* __restrict__ lossA, int row0)
{
  int r = blockIdx.x * 256 + threadIdx.x;  // chunk-local
  int gi = row0 + r;
  int bidx = (int)(pk[gi] & 0xFFFFFFFFull);
  idx[gi] = bidx;
  const float4* zp = (const float4*)(z + (size_t)r * Dd);
  const float4* cr = (const float4*)(cbf + (size_t)bidx * Dd);
  float ls = 0.f;
#pragma unroll
  for (int i = 0; i < 16; ++i) {
    float4 zv = zp[i], cv = cr[i];
    float e0 = zv.x - cv.x, e1 = zv.y - cv.y;
    float e2 = zv.z - cv.z, e3 = zv.w - cv.w;
    ls += e0 * e0 + e1 * e1 + e2 * e2 + e3 * e3;
  }
#pragma unroll
  for (int off = 32; off > 0; off >>= 1) ls += __shfl_down(ls, off);
  if ((threadIdx.x & 63) == 0) atomicAdd(lossA, ls);
}

__global__ void k_loss_final(const float* __restrict__ a, float* __restrict__ out)
{
  if (threadIdx.x == 0) {
    float l = a[0] / (float)(ROWS * Dd);
    out[0] = l;
    out[1] = l;
  }
}

// ---------- dec conv1 (1x1, 64->32, ReLU) ----------
__global__ __launch_bounds__(256) void k_dec1(
    const int* __restrict__ idx, const float* __restrict__ cbf,
    const float* __restrict__ w, const float* __restrict__ b,
    float* __restrict__ d1, int row0)
{
  int bid = blockIdx.x;
  int y = bid & 63, n = bid >> 6;
  __shared__ float sZ[64 * 65];
  __shared__ float sW[32 * 65];
  int tid = threadIdx.x;
  int base = row0 + (n * H2 + y) * W2;
  {
    int d = tid & 63, x0 = tid >> 6;
    for (int k = 0; k < 16; ++k) {
      int xx = x0 + 4 * k;
      int ci = idx[base + xx];
      sZ[xx * 65 + d] = cbf[ci * Dd + d];
    }
  }
  for (int i = tid; i < 32 * Dd; i += 256) {
    int co = i >> 6, d = i & 63;
    sW[co * 65 + d] = w[i];
  }
  __syncthreads();
  int lx = tid & 63, cg = tid >> 6;
  float acc[8];
#pragma unroll
  for (int j = 0; j < 8; ++j) acc[j] = 0.f;
  for (int d = 0; d < Dd; ++d) {
    float u = sZ[lx * 65 + d];
#pragma unroll
    for (int j = 0; j < 8; ++j)
      acc[j] += u * sW[(cg * 8 + j) * 65 + d];
  }
#pragma unroll
  for (int j = 0; j < 8; ++j) {
    int co = cg * 8 + j;
    float v = acc[j] + b[co];
    v = v > 0.f ? v : 0.f;
    d1[((n * C2 + co) * H2 + y) * W2 + lx] = v;
  }
}

// ---------- composed upsample2x+conv3x3 as 4-phase conv on low-res grid ----------
template <int Ci, int Hi, int Co, int COCH, bool RELU>
__global__ __launch_bounds__(256) void k_upconv2x(
    const float* __restrict__ I, const float* __restrict__ k2,
    const float* __restrict__ bias, float* __restrict__ O, int n0)
{
  constexpr int TT = Hi / 32, NCG = Co / COCH, Ho = 2 * Hi, Wo = 2 * Hi;
  int bid = blockIdx.x;
  int tx = bid % TT; bid /= TT;
  int ty = bid % TT; bid /= TT;
  int cg = bid % NCG; bid /= NCG;
  int n = bid;
  int Y0 = ty * 32, X0 = tx * 32;
  __shared__ float sI[4][34 * 35];
  int tid = threadIdx.x;
  int lx = tid & 15, ly = tid >> 4;  // 16x16 threads, each 2x2 low-res px
  float4 acc[COCH][2][2];
#pragma unroll
  for (int j = 0; j < COCH; ++j)
#pragma unroll
    for (int a = 0; a < 2; ++a)
#pragma unroll
      for (int b = 0; b < 2; ++b) acc[j][a][b] = make_float4(0.f, 0.f, 0.f, 0.f);
  const float* kbase = k2 + (size_t)cg * COCH * Ci * 36;
  for (int c0 = 0; c0 < Ci; c0 += 4) {
    __syncthreads();
    for (int i = tid; i < 4 * 34 * 34; i += 256) {
      int s = i / 1156, r2 = i % 1156;
      int rr = r2 / 34, cc2 = r2 % 34;
      int gy = Y0 - 1 + rr; gy = gy < 0 ? 0 : (gy > Hi - 1 ? Hi - 1 : gy);
      int gx = X0 - 1 + cc2; gx = gx < 0 ? 0 : (gx > Hi - 1 ? Hi - 1 : gx);
      sI[s][rr * 35 + cc2] = I[((size_t)n * Ci + c0 + s) * Hi * Hi + gy * Hi + gx];
    }
    __syncthreads();
#pragma unroll
    for (int s = 0; s < 4; ++s) {
      float t[4][4];
#pragma unroll
      for (int r = 0; r < 4; ++r)
#pragma unroll
        for (int c = 0; c < 4; ++c)
          t[r][c] = sI[s][(2 * ly + r) * 35 + 2 * lx + c];
#pragma unroll
      for (int j = 0; j < COCH; ++j) {
        const float* kj = kbase + ((size_t)j * Ci + c0 + s) * 36;
#pragma unroll
        for (int a = 0; a < 3; ++a)
#pragma unroll
          for (int b = 0; b < 3; ++b) {
            float w00 = kj[a * 3 + b];
            float w01 = kj[9 + a * 3 + b];
            float w10 = kj[18 + a * 3 + b];
            float w11 = kj[27 + a * 3 + b];
#pragma unroll
            for (int pyy = 0; pyy < 2; ++pyy) {
              float i0 = t[pyy + a][b];
              float i1 = t[pyy + a][b + 1];
              acc[j][pyy][0].x += i0 * w00;
              acc[j][pyy][0].y += i0 * w01;
              acc[j][pyy][0].z += i1 * w00;
              acc[j][pyy][0].w += i1 * w01;
              acc[j][pyy][1].x += i0 * w10;
              acc[j][pyy][1].y += i0 * w11;
              acc[j][pyy][1].z += i1 * w10;
              acc[j][pyy][1].w += i1 * w11;
            }
          }
      }
    }
  }
  int ox = 2 * X0 + 4 * lx;
#pragma unroll
  for (int j = 0; j < COCH; ++j) {
    int co = cg * COCH + j;
    float bv = bias[co];
#pragma unroll
    for (int pyy = 0; pyy < 2; ++pyy) {
      int oy0 = 2 * (Y0 + 2 * ly + pyy);
#pragma unroll
      for (int py = 0; py < 2; ++py) {
        float4 v = acc[j][pyy][py];
        v.x += bv; v.y += bv; v.z += bv; v.w += bv;
        if (RELU) {
          v.x = v.x > 0.f ? v.x : 0.f;
          v.y = v.y > 0.f ? v.y : 0.f;
          v.z = v.z > 0.f ? v.z : 0.f;
          v.w = v.w > 0.f ? v.w : 0.f;
        }
        size_t off = (((size_t)(n0 + n) * Co + co) * Ho + oy0 + py) * Wo + ox;
        *(float4*)&O[off] = v;
      }
    }
  }
}

// ---------- exact direct computation of the output border ring ----------
template <int Ci, int Hi, int Co, int CG, bool RELU>
__global__ __launch_bounds__(256) void k_upfix(
    const float* __restrict__ I, const float* __restrict__ w,
    const float* __restrict__ bias, float* __restrict__ O, int CHn, int n0)
{
  constexpr int Ho = 2 * Hi, Wo = 2 * Hi;
  constexpr int RING = 2 * (Ho + Wo) - 4;
  constexpr int NCG = Co / CG;
  int gi = blockIdx.x * 256 + threadIdx.x;
  if (gi >= CHn * NCG * RING) return;
  int p = gi % RING;
  int cgrp = (gi / RING) % NCG;
  int n = gi / (RING * NCG);
  int u, v;
  if (p < Wo)            { u = 0;       v = p; }
  else if (p < 2 * Wo)   { u = Ho - 1;  v = p - Wo; }
  else { int q = p - 2 * Wo; u = 1 + (q >> 1); v = (q & 1) ? (Wo - 1) : 0; }
  float acc[CG];
#pragma unroll
  for (int j = 0; j < CG; ++j) acc[j] = 0.f;
  for (int ci = 0; ci < Ci; ++ci) {
    const float* Ip = I + ((size_t)n * Ci + ci) * Hi * Hi;
    float U[9];
#pragma unroll
    for (int dy = 0; dy < 3; ++dy)
#pragma unroll
      for (int dx = 0; dx < 3; ++dx) {
        int vy = u - 1 + dy, vx = v - 1 + dx;
        float val = 0.f;
        if (vy >= 0 && vy < Ho && vx >= 0 && vx < Wo) {
          int ky0, ky1, kx0, kx1; float ay0, ax0;
          if (vy & 1) { ky0 = vy >> 1; ky1 = ky0 + 1; ay0 = .75f; }
          else        { ky1 = vy >> 1; ky0 = ky1 - 1; ay0 = .25f; }
          if (vx & 1) { kx0 = vx >> 1; kx1 = kx0 + 1; ax0 = .75f; }
          else        { kx1 = vx >> 1; kx0 = kx1 - 1; ax0 = .25f; }
          ky0 = ky0 < 0 ? 0 : (ky0 > Hi - 1 ? Hi - 1 : ky0);
          ky1 = ky1 < 0 ? 0 : (ky1 > Hi - 1 ? Hi - 1 : ky1);
          kx0 = kx0 < 0 ? 0 : (kx0 > Hi - 1 ? Hi - 1 : kx0);
          kx1 = kx1 < 0 ? 0 : (kx1 > Hi - 1 ? Hi - 1 : kx1);
          float ay1 = 1.f - ay0, ax1 = 1.f - ax0;
          float r0 = ax0 * Ip[ky0 * Hi + kx0] + ax1 * Ip[ky0 * Hi + kx1];
          float r1 = ax0 * Ip[ky1 * Hi + kx0] + ax1 * Ip[ky1 * Hi + kx1];
          val = ay0 * r0 + ay1 * r1;
        }
        U[dy * 3 + dx] = val;
      }
#pragma unroll
    for (int j = 0; j < CG; ++j) {
      const float* wp = w + ((size_t)(cgrp * CG + j) * Ci + ci) * 9;
#pragma unroll
      for (int tp = 0; tp < 9; ++tp) acc[j] += U[tp] * wp[tp];
    }
  }
#pragma unroll
  for (int j = 0; j < CG; ++j) {
    int co = cgrp * CG + j;
    float val = acc[j] + bias[co];
    if (RELU) val = val > 0.f ? val : 0.f;
    O[((size_t)((n0 + n) * Co + co) * Ho + u) * Wo + v] = val;
  }
}

extern "C" void kernel_launch(void* const* d_in, const int* in_sizes, int n_in,
                              void* d_out, int out_size, void* d_ws, size_t ws_size,
                              hipStream_t stream)
{
  const float* x      = (const float*)d_in[0];
  const float* cb     = (const float*)d_in[1];
  const float* enc_w1 = (const float*)d_in[2];
  const float* enc_b1 = (const float*)d_in[3];
  const float* enc_w2 = (const float*)d_in[4];
  const float* enc_b2 = (const float*)d_in[5];
  const float* enc_w3 = (const float*)d_in[6];
  const float* enc_b3 = (const float*)d_in[7];
  const float* dec_w1 = (const float*)d_in[8];
  const float* dec_b1 = (const float*)d_in[9];
  const float* dec_w2 = (const float*)d_in[10];
  const float* dec_b2 = (const float*)d_in[11];
  const float* dec_w3 = (const float*)d_in[12];
  const float* dec_b3 = (const float*)d_in[13];

  float* ws = (float*)d_ws;
  float* lossA = ws;                                  // 64
  int* idx = (int*)(lossA + 64);                      // ROWS ints
  unsigned long long* pk = (unsigned long long*)(idx + ROWS);  // ROWS ull
  float* k2a = (float*)(pk + ROWS);                   // 73728
  float* k2b = k2a + K2A_FLOATS;                      // 6912
  float* chunkbuf = k2b + K2B_FLOATS + 64;

  int CH = 1;
  for (int c = 32; c >= 1; c >>= 1) {
    size_t need = ((size_t)FIX_FLOATS + (size_t)(H1_PER_N + Z_PER_N + H2_PER_N) * c) * 4;
    if (need <= ws_size) { CH = c; break; }
  }
  float* h1 = chunkbuf;                   // CH * 1,048,576  (reused as d2)
  float* z  = h1 + (size_t)H1_PER_N * CH; // CH * 262,144
  float* h2 = z + (size_t)Z_PER_N * CH;   // CH * 131,072    (reused as d1)

  k_init<<<ROWS / 256, 256, 0, stream>>>(lossA, pk);
  k_wtrans<<<(64 * 32 + 255) / 256, 256, 0, stream>>>(dec_w2, k2a, 64 * 32);
  k_wtrans<<<1, 256, 0, stream>>>(dec_w3, k2b, 3 * 64);

  float* out = (float*)d_out;

  for (int n0 = 0; n0 < Bn; n0 += CH) {
    int row0 = n0 * H2 * W2;
    k_conv1<<<CH * 128, 256, 0, stream>>>(x, enc_w1, enc_b1, h1, n0);
    k_conv2<<<CH * 16, 256, 0, stream>>>(h1, enc_w2, enc_b2, h2);
    k_conv3z<<<CH * 64, 256, 0, stream>>>(h2, enc_w3, enc_b3, z);
    // 4-way codebook split: grid = rowblocks(CH*16) x 4
    k_vq<<<CH * 16 * 4, 256, 0, stream>>>(z, cb, pk, row0);
    k_vqfin<<<CH * 16, 256, 0, stream>>>(z, cb, pk, idx, lossA, row0);
    k_dec1<<<CH * 64, 256, 0, stream>>>(idx, cb, dec_w1, dec_b1, h2, row0);
    // d1 (h2) -> d2 (h1): 32ch 64x64 -> 64ch 128x128, ReLU
    k_upconv2x<32, 64, 64, 4, true><<<CH * 16 * 2 * 2, 256, 0, stream>>>(
        h2, k2a, dec_b2, h1, 0);
    k_upfix<32, 64, 64, 16, true>
        <<<(CH * 4 * 508 + 255) / 256, 256, 0, stream>>>(
            h2, dec_w2, dec_b2, h1, CH, 0);
    // d2 (h1) -> recon: 64ch 128x128 -> 3ch 256x256, f32 out at offset 2
    k_upconv2x<64, 128, 3, 3, false><<<CH * 1 * 4 * 4, 256, 0, stream>>>(
        h1, k2b, dec_b3, out + 2, n0);
    k_upfix<64, 128, 3, 3, false>
        <<<(CH * 1 * 1020 + 255) / 256, 256, 0, stream>>>(
            h1, dec_w3, dec_b3, out + 2, CH, n0);
  }
  k_loss_final<<<1, 64, 0, stream>>>(lossA, out);
}

// Round 8
// 1520.490 us; speedup vs baseline: 1.3893x; 1.1371x over previous
//
#include <hip/hip_runtime.h>
#include <hip/hip_bf16.h>

static constexpr int Bn = 32;
static constexpr int Hin = 256, Win = 256;
static constexpr int C1 = 64, H1 = 128, W1 = 128;
static constexpr int C2 = 32, H2 = 64, W2 = 64;
static constexpr int Dd = 64;    // latent dim
static constexpr int Kc = 512;   // codebook entries
static constexpr int ROWS = Bn * H2 * W2;  // 131072

// ws layout (floats): lossA(64) | idx(ROWS int) | pk(ROWS ull) | k2a | k2b | chunk
static constexpr int K2A_FLOATS = 64 * 32 * 36;  // 73728
static constexpr int K2B_FLOATS = 3 * 64 * 36;   // 6912
static constexpr int FIX_FLOATS = 64 + ROWS + 2 * ROWS + K2A_FLOATS + K2B_FLOATS + 64;
static constexpr int H1_PER_N = C1 * H1 * W1;    // 1,048,576
static constexpr int Z_PER_N  = H2 * W2 * Dd;    // 262,144
static constexpr int H2_PER_N = C2 * H2 * W2;    // 131,072

// ---------- init: zero loss accum, preset packed argmin keys ----------
__global__ __launch_bounds__(256) void k_init(
    float* __restrict__ lossA, unsigned long long* __restrict__ pk)
{
  int i = blockIdx.x * 256 + threadIdx.x;
  if (i < 64) lossA[i] = 0.f;
  pk[i] = 0xFFFFFFFFFFFFFFFFull;
}

// ---------- upsample-conv weight compose: K'[py,px] = Ay^T W Ax ----------
__global__ __launch_bounds__(256) void k_wtrans(
    const float* __restrict__ w, float* __restrict__ k2, int N)
{
  int i = blockIdx.x * 256 + threadIdx.x;
  if (i >= N) return;
  float W[3][3];
#pragma unroll
  for (int ty = 0; ty < 3; ++ty)
#pragma unroll
    for (int tx = 0; tx < 3; ++tx) W[ty][tx] = w[i * 9 + ty * 3 + tx];
  const float A[2][3][3] = {
      {{.75f, .25f, 0.f}, {.25f, .75f, 0.f}, {0.f, .75f, .25f}},
      {{.25f, .75f, 0.f}, {0.f, .75f, .25f}, {0.f, .25f, .75f}}};
#pragma unroll
  for (int py = 0; py < 2; ++py)
#pragma unroll
    for (int px = 0; px < 2; ++px)
#pragma unroll
      for (int a = 0; a < 3; ++a)
#pragma unroll
        for (int b = 0; b < 3; ++b) {
          float v = 0.f;
#pragma unroll
          for (int ty = 0; ty < 3; ++ty)
#pragma unroll
            for (int tx = 0; tx < 3; ++tx)
              v += W[ty][tx] * A[py][ty][a] * A[px][tx][b];
          k2[(size_t)i * 36 + (py * 2 + px) * 9 + a * 3 + b] = v;
        }
}

// ---------- enc conv1: 3->64, 3x3, s2, p1, ReLU ----------
__global__ __launch_bounds__(256) void k_conv1(
    const float* __restrict__ x, const float* __restrict__ w,
    const float* __restrict__ b, float* __restrict__ h1, int n0)
{
  int bid = blockIdx.x;
  int xt = bid & 1, yt = (bid >> 1) & 15, cc = (bid >> 5) & 3, n = bid >> 7;
  int X0 = xt * 64, Y0 = yt * 8, co0 = cc * 16;
  __shared__ float sIn[3][17][130];
  int tid = threadIdx.x;
  for (int i = tid; i < 3 * 17 * 130; i += 256) {
    int ci = i / (17 * 130);
    int rr = (i / 130) % 17;
    int ccx = i % 130;
    int gy = 2 * Y0 - 1 + rr, gx = 2 * X0 - 1 + ccx;
    float v = 0.f;
    if (gy >= 0 && gy < Hin && gx >= 0 && gx < Win)
      v = x[(((size_t)(n0 + n) * 3 + ci) * Hin + gy) * Win + gx];
    sIn[ci][rr][ccx] = v;
  }
  __syncthreads();
  int lx = tid & 63, ys = tid >> 6;
  float acc[16][2];
#pragma unroll
  for (int c = 0; c < 16; ++c) { acc[c][0] = 0.f; acc[c][1] = 0.f; }
#pragma unroll
  for (int ci = 0; ci < 3; ++ci)
#pragma unroll
    for (int ky = 0; ky < 3; ++ky)
#pragma unroll
      for (int kx = 0; kx < 3; ++kx) {
        float u0 = sIn[ci][2 * ys + ky][2 * lx + kx];
        float u1 = sIn[ci][2 * ys + 8 + ky][2 * lx + kx];
#pragma unroll
        for (int c = 0; c < 16; ++c) {
          float wv = w[((co0 + c) * 3 + ci) * 9 + ky * 3 + kx];
          acc[c][0] += u0 * wv;
          acc[c][1] += u1 * wv;
        }
      }
#pragma unroll
  for (int c = 0; c < 16; ++c) {
    float bv = b[co0 + c];
    float v0 = acc[c][0] + bv; v0 = v0 > 0.f ? v0 : 0.f;
    float v1 = acc[c][1] + bv; v1 = v1 > 0.f ? v1 : 0.f;
    h1[((n * C1 + co0 + c) * H1 + Y0 + ys) * W1 + X0 + lx] = v0;
    h1[((n * C1 + co0 + c) * H1 + Y0 + ys + 4) * W1 + X0 + lx] = v1;
  }
}

// ---------- enc conv2: 64->32, 3x3, s2, p1, ReLU ----------
// v2: 4-way co split (grid CH*32 = 4 blocks/CU) + lane-mapped cheap staging.
// block: 8 out rows x 64 cols x 8 co; thread: (lx, ys) -> 2 y x 8 co accs.
__global__ __launch_bounds__(256) void k_conv2(
    const float* __restrict__ h1, const float* __restrict__ w,
    const float* __restrict__ b, float* __restrict__ h2)
{
  int bid = blockIdx.x;
  int yt = bid & 7, cg = (bid >> 3) & 3, n = bid >> 5;
  int Y0 = yt * 8, co0 = cg * 8;
  __shared__ float sIn[4][17][130];
  int tid = threadIdx.x;
  int lane = tid & 63, ci2 = tid >> 6;
  int lx = lane, ys = ci2;
  float acc[8][2];
#pragma unroll
  for (int c = 0; c < 8; ++c) { acc[c][0] = 0.f; acc[c][1] = 0.f; }
  for (int cb0 = 0; cb0 < C1; cb0 += 4) {
    __syncthreads();
    {
      // each 64-lane group stages one input channel: 17 rows x 130 cols
      const float* src = h1 + ((size_t)(n * C1 + cb0 + ci2)) * H1 * W1;
      float* dst = &sIn[ci2][0][0];
#pragma unroll 1
      for (int rr = 0; rr < 17; ++rr) {
        int gy = 2 * Y0 - 1 + rr;
        bool yok = (gy >= 0) & (gy < H1);
        const float* rowp = src + gy * W1;
        float v0 = (yok && lane > 0) ? rowp[lane - 1] : 0.f;
        float v1 = yok ? rowp[lane + 63] : 0.f;
        dst[rr * 130 + lane] = v0;
        dst[rr * 130 + 64 + lane] = v1;
        if (lane < 2) {
          float v2 = (yok && lane == 0) ? rowp[127] : 0.f;
          dst[rr * 130 + 128 + lane] = v2;
        }
      }
    }
    __syncthreads();
#pragma unroll
    for (int ci = 0; ci < 4; ++ci)
#pragma unroll
      for (int ky = 0; ky < 3; ++ky)
#pragma unroll
        for (int kx = 0; kx < 3; ++kx) {
          float u0 = sIn[ci][2 * ys + ky][2 * lx + kx];
          float u1 = sIn[ci][2 * ys + 8 + ky][2 * lx + kx];
#pragma unroll
          for (int c = 0; c < 8; ++c) {
            float wv = w[((co0 + c) * C1 + cb0 + ci) * 9 + ky * 3 + kx];
            acc[c][0] += u0 * wv;
            acc[c][1] += u1 * wv;
          }
        }
  }
#pragma unroll
  for (int c = 0; c < 8; ++c) {
    float bv = b[co0 + c];
    float v0 = acc[c][0] + bv; v0 = v0 > 0.f ? v0 : 0.f;
    float v1 = acc[c][1] + bv; v1 = v1 > 0.f ? v1 : 0.f;
    h2[((n * C2 + co0 + c) * H2 + Y0 + ys) * W2 + lx] = v0;
    h2[((n * C2 + co0 + c) * H2 + Y0 + ys + 4) * W2 + lx] = v1;
  }
}

// ---------- enc conv3 (1x1, 32->64) -> z in [row][64] ----------
__global__ __launch_bounds__(256) void k_conv3z(
    const float* __restrict__ h2, const float* __restrict__ w,
    const float* __restrict__ b, float* __restrict__ z)
{
  int bid = blockIdx.x;
  int y = bid & 63, n = bid >> 6;
  __shared__ float sH[C2][64];
  __shared__ float sW[Dd * 33];
  int tid = threadIdx.x;
  for (int i = tid; i < C2 * 64; i += 256) {
    int ci = i >> 6, xx = i & 63;
    sH[ci][xx] = h2[((n * C2 + ci) * H2 + y) * W2 + xx];
  }
  for (int i = tid; i < Dd * C2; i += 256) {
    int d = i >> 5, ci = i & 31;
    sW[d * 33 + ci] = w[i];
  }
  __syncthreads();
  int dg = tid & 3, lx = tid >> 2;
  float acc[16];
#pragma unroll
  for (int j = 0; j < 16; ++j) acc[j] = 0.f;
  for (int ci = 0; ci < C2; ++ci) {
    float u = sH[ci][lx];
#pragma unroll
    for (int j = 0; j < 16; ++j)
      acc[j] += u * sW[(dg * 16 + j) * 33 + ci];
  }
  int row = (n * H2 + y) * W2 + lx;
#pragma unroll
  for (int j = 0; j < 16; ++j)
    z[row * Dd + dg * 16 + j] = acc[j] + b[dg * 16 + j];
}

// ---------- VQ main: 4-way codebook split, packed atomicMin argmin ----------
__global__ __launch_bounds__(256) void k_vq(
    const float* __restrict__ z, const float* __restrict__ cbf,
    unsigned long long* __restrict__ pk, int row0)
{
  __shared__ float c2s[128];
  int bid = blockIdx.x;
  int sp = bid & 3, rb = bid >> 2;
  int c0 = sp * 128;
  int tid = threadIdx.x;
  if (tid < 128) {
    const float* cr = cbf + (size_t)(c0 + tid) * Dd;
    float s = 0.f;
#pragma unroll
    for (int d = 0; d < Dd; ++d) { float v = cr[d]; s += v * v; }
    c2s[tid] = s;
  }
  __syncthreads();
  int r = rb * 256 + tid;  // chunk-local row
  float4 zr[16];
  const float4* zp = (const float4*)(z + (size_t)r * Dd);
#pragma unroll
  for (int i = 0; i < 16; ++i) zr[i] = zp[i];
  float best = 1e30f; int bidx = c0;
  for (int c = 0; c < 128; ++c) {
    const float* __restrict__ cr = cbf + (size_t)(c0 + c) * Dd;
    float d0 = 0.f, d1 = 0.f, d2a = 0.f, d3 = 0.f;
#pragma unroll
    for (int i = 0; i < 16; ++i) {
      d0 += zr[i].x * cr[4 * i + 0];
      d1 += zr[i].y * cr[4 * i + 1];
      d2a += zr[i].z * cr[4 * i + 2];
      d3 += zr[i].w * cr[4 * i + 3];
    }
    float dot = (d0 + d1) + (d2a + d3);
    float dist = c2s[c] - 2.f * dot;
    if (dist < best) { best = dist; bidx = c0 + c; }
  }
  unsigned int u = __float_as_uint(best);
  unsigned int key32 = (u & 0x80000000u) ? ~u : (u | 0x80000000u);
  unsigned long long key =
      ((unsigned long long)key32 << 32) | (unsigned int)bidx;
  atomicMin(&pk[row0 + r], key);
}

// ---------- VQ merge: extract idx, accumulate loss ----------
__global__ __launch_bounds__(256) void k_vqfin(
    const float* __restrict__ z, const float* __restrict__ cbf,
    const unsigned long long* __restrict__ pk, int* __restrict__ idx,
    float* __restrict__ lossA, int row0)
{
  int r = blockIdx.x * 256 + threadIdx.x;  // chunk-local
  int gi = row0 + r;
  int bidx = (int)(pk[gi] & 0xFFFFFFFFull);
  idx[gi] = bidx;
  const float4* zp = (const float4*)(z + (size_t)r * Dd);
  const float4* cr = (const float4*)(cbf + (size_t)bidx * Dd);
  float ls = 0.f;
#pragma unroll
  for (int i = 0; i < 16; ++i) {
    float4 zv = zp[i], cv = cr[i];
    float e0 = zv.x - cv.x, e1 = zv.y - cv.y;
    float e2 = zv.z - cv.z, e3 = zv.w - cv.w;
    ls += e0 * e0 + e1 * e1 + e2 * e2 + e3 * e3;
  }
#pragma unroll
  for (int off = 32; off > 0; off >>= 1) ls += __shfl_down(ls, off);
  if ((threadIdx.x & 63) == 0) atomicAdd(lossA, ls);
}

__global__ void k_loss_final(const float* __restrict__ a, float* __restrict__ out)
{
  if (threadIdx.x == 0) {
    float l = a[0] / (float)(ROWS * Dd);
    out[0] = l;
    out[1] = l;
  }
}

// ---------- dec conv1 (1x1, 64->32, ReLU) ----------
__global__ __launch_bounds__(256) void k_dec1(
    const int* __restrict__ idx, const float* __restrict__ cbf,
    const float* __restrict__ w, const float* __restrict__ b,
    float* __restrict__ d1, int row0)
{
  int bid = blockIdx.x;
  int y = bid & 63, n = bid >> 6;
  __shared__ float sZ[64 * 65];
  __shared__ float sW[32 * 65];
  int tid = threadIdx.x;
  int base = row0 + (n * H2 + y) * W2;
  {
    int d = tid & 63, x0 = tid >> 6;
    for (int k = 0; k < 16; ++k) {
      int xx = x0 + 4 * k;
      int ci = idx[base + xx];
      sZ[xx * 65 + d] = cbf[ci * Dd + d];
    }
  }
  for (int i = tid; i < 32 * Dd; i += 256) {
    int co = i >> 6, d = i & 63;
    sW[co * 65 + d] = w[i];
  }
  __syncthreads();
  int lx = tid & 63, cg = tid >> 6;
  float acc[8];
#pragma unroll
  for (int j = 0; j < 8; ++j) acc[j] = 0.f;
  for (int d = 0; d < Dd; ++d) {
    float u = sZ[lx * 65 + d];
#pragma unroll
    for (int j = 0; j < 8; ++j)
      acc[j] += u * sW[(cg * 8 + j) * 65 + d];
  }
#pragma unroll
  for (int j = 0; j < 8; ++j) {
    int co = cg * 8 + j;
    float v = acc[j] + b[co];
    v = v > 0.f ? v : 0.f;
    d1[((n * C2 + co) * H2 + y) * W2 + lx] = v;
  }
}

// ---------- composed upsample2x+conv3x3 as 4-phase conv on low-res grid ----------
template <int Ci, int Hi, int Co, int COCH, bool RELU>
__global__ __launch_bounds__(256) void k_upconv2x(
    const float* __restrict__ I, const float* __restrict__ k2,
    const float* __restrict__ bias, float* __restrict__ O, int n0)
{
  constexpr int TT = Hi / 32, NCG = Co / COCH, Ho = 2 * Hi, Wo = 2 * Hi;
  int bid = blockIdx.x;
  int tx = bid % TT; bid /= TT;
  int ty = bid % TT; bid /= TT;
  int cg = bid % NCG; bid /= NCG;
  int n = bid;
  int Y0 = ty * 32, X0 = tx * 32;
  __shared__ float sI[4][34 * 35];
  int tid = threadIdx.x;
  int lx = tid & 15, ly = tid >> 4;  // 16x16 threads, each 2x2 low-res px
  float4 acc[COCH][2][2];
#pragma unroll
  for (int j = 0; j < COCH; ++j)
#pragma unroll
    for (int a = 0; a < 2; ++a)
#pragma unroll
      for (int b = 0; b < 2; ++b) acc[j][a][b] = make_float4(0.f, 0.f, 0.f, 0.f);
  const float* kbase = k2 + (size_t)cg * COCH * Ci * 36;
  for (int c0 = 0; c0 < Ci; c0 += 4) {
    __syncthreads();
    for (int i = tid; i < 4 * 34 * 34; i += 256) {
      int s = i / 1156, r2 = i % 1156;
      int rr = r2 / 34, cc2 = r2 % 34;
      int gy = Y0 - 1 + rr; gy = gy < 0 ? 0 : (gy > Hi - 1 ? Hi - 1 : gy);
      int gx = X0 - 1 + cc2; gx = gx < 0 ? 0 : (gx > Hi - 1 ? Hi - 1 : gx);
      sI[s][rr * 35 + cc2] = I[((size_t)n * Ci + c0 + s) * Hi * Hi + gy * Hi + gx];
    }
    __syncthreads();
#pragma unroll
    for (int s = 0; s < 4; ++s) {
      float t[4][4];
#pragma unroll
      for (int r = 0; r < 4; ++r)
#pragma unroll
        for (int c = 0; c < 4; ++c)
          t[r][c] = sI[s][(2 * ly + r) * 35 + 2 * lx + c];
#pragma unroll
      for (int j = 0; j < COCH; ++j) {
        const float* kj = kbase + ((size_t)j * Ci + c0 + s) * 36;
#pragma unroll
        for (int a = 0; a < 3; ++a)
#pragma unroll
          for (int b = 0; b < 3; ++b) {
            float w00 = kj[a * 3 + b];
            float w01 = kj[9 + a * 3 + b];
            float w10 = kj[18 + a * 3 + b];
            float w11 = kj[27 + a * 3 + b];
#pragma unroll
            for (int pyy = 0; pyy < 2; ++pyy) {
              float i0 = t[pyy + a][b];
              float i1 = t[pyy + a][b + 1];
              acc[j][pyy][0].x += i0 * w00;
              acc[j][pyy][0].y += i0 * w01;
              acc[j][pyy][0].z += i1 * w00;
              acc[j][pyy][0].w += i1 * w01;
              acc[j][pyy][1].x += i0 * w10;
              acc[j][pyy][1].y += i0 * w11;
              acc[j][pyy][1].z += i1 * w10;
              acc[j][pyy][1].w += i1 * w11;
            }
          }
      }
    }
  }
  int ox = 2 * X0 + 4 * lx;
#pragma unroll
  for (int j = 0; j < COCH; ++j) {
    int co = cg * COCH + j;
    float bv = bias[co];
#pragma unroll
    for (int pyy = 0; pyy < 2; ++pyy) {
      int oy0 = 2 * (Y0 + 2 * ly + pyy);
#pragma unroll
      for (int py = 0; py < 2; ++py) {
        float4 v = acc[j][pyy][py];
        v.x += bv; v.y += bv; v.z += bv; v.w += bv;
        if (RELU) {
          v.x = v.x > 0.f ? v.x : 0.f;
          v.y = v.y > 0.f ? v.y : 0.f;
          v.z = v.z > 0.f ? v.z : 0.f;
          v.w = v.w > 0.f ? v.w : 0.f;
        }
        size_t off = (((size_t)(n0 + n) * Co + co) * Ho + oy0 + py) * Wo + ox;
        *(float4*)&O[off] = v;
      }
    }
  }
}

// ---------- exact direct computation of the output border ring ----------
template <int Ci, int Hi, int Co, int CG, bool RELU>
__global__ __launch_bounds__(256) void k_upfix(
    const float* __restrict__ I, const float* __restrict__ w,
    const float* __restrict__ bias, float* __restrict__ O, int CHn, int n0)
{
  constexpr int Ho = 2 * Hi, Wo = 2 * Hi;
  constexpr int RING = 2 * (Ho + Wo) - 4;
  constexpr int NCG = Co / CG;
  int gi = blockIdx.x * 256 + threadIdx.x;
  if (gi >= CHn * NCG * RING) return;
  int p = gi % RING;
  int cgrp = (gi / RING) % NCG;
  int n = gi / (RING * NCG);
  int u, v;
  if (p < Wo)            { u = 0;       v = p; }
  else if (p < 2 * Wo)   { u = Ho - 1;  v = p - Wo; }
  else { int q = p - 2 * Wo; u = 1 + (q >> 1); v = (q & 1) ? (Wo - 1) : 0; }
  float acc[CG];
#pragma unroll
  for (int j = 0; j < CG; ++j) acc[j] = 0.f;
  for (int ci = 0; ci < Ci; ++ci) {
    const float* Ip = I + ((size_t)n * Ci + ci) * Hi * Hi;
    float U[9];
#pragma unroll
    for (int dy = 0; dy < 3; ++dy)
#pragma unroll
      for (int dx = 0; dx < 3; ++dx) {
        int vy = u - 1 + dy, vx = v - 1 + dx;
        float val = 0.f;
        if (vy >= 0 && vy < Ho && vx >= 0 && vx < Wo) {
          int ky0, ky1, kx0, kx1; float ay0, ax0;
          if (vy & 1) { ky0 = vy >> 1; ky1 = ky0 + 1; ay0 = .75f; }
          else        { ky1 = vy >> 1; ky0 = ky1 - 1; ay0 = .25f; }
          if (vx & 1) { kx0 = vx >> 1; kx1 = kx0 + 1; ax0 = .75f; }
          else        { kx1 = vx >> 1; kx0 = kx1 - 1; ax0 = .25f; }
          ky0 = ky0 < 0 ? 0 : (ky0 > Hi - 1 ? Hi - 1 : ky0);
          ky1 = ky1 < 0 ? 0 : (ky1 > Hi - 1 ? Hi - 1 : ky1);
          kx0 = kx0 < 0 ? 0 : (kx0 > Hi - 1 ? Hi - 1 : kx0);
          kx1 = kx1 < 0 ? 0 : (kx1 > Hi - 1 ? Hi - 1 : kx1);
          float ay1 = 1.f - ay0, ax1 = 1.f - ax0;
          float r0 = ax0 * Ip[ky0 * Hi + kx0] + ax1 * Ip[ky0 * Hi + kx1];
          float r1 = ax0 * Ip[ky1 * Hi + kx0] + ax1 * Ip[ky1 * Hi + kx1];
          val = ay0 * r0 + ay1 * r1;
        }
        U[dy * 3 + dx] = val;
      }
#pragma unroll
    for (int j = 0; j < CG; ++j) {
      const float* wp = w + ((size_t)(cgrp * CG + j) * Ci + ci) * 9;
#pragma unroll
      for (int tp = 0; tp < 9; ++tp) acc[j] += U[tp] * wp[tp];
    }
  }
#pragma unroll
  for (int j = 0; j < CG; ++j) {
    int co = cgrp * CG + j;
    float val = acc[j] + bias[co];
    if (RELU) val = val > 0.f ? val : 0.f;
    O[((size_t)((n0 + n) * Co + co) * Ho + u) * Wo + v] = val;
  }
}

extern "C" void kernel_launch(void* const* d_in, const int* in_sizes, int n_in,
                              void* d_out, int out_size, void* d_ws, size_t ws_size,
                              hipStream_t stream)
{
  const float* x      = (const float*)d_in[0];
  const float* cb     = (const float*)d_in[1];
  const float* enc_w1 = (const float*)d_in[2];
  const float* enc_b1 = (const float*)d_in[3];
  const float* enc_w2 = (const float*)d_in[4];
  const float* enc_b2 = (const float*)d_in[5];
  const float* enc_w3 = (const float*)d_in[6];
  const float* enc_b3 = (const float*)d_in[7];
  const float* dec_w1 = (const float*)d_in[8];
  const float* dec_b1 = (const float*)d_in[9];
  const float* dec_w2 = (const float*)d_in[10];
  const float* dec_b2 = (const float*)d_in[11];
  const float* dec_w3 = (const float*)d_in[12];
  const float* dec_b3 = (const float*)d_in[13];

  float* ws = (float*)d_ws;
  float* lossA = ws;                                  // 64
  int* idx = (int*)(lossA + 64);                      // ROWS ints
  unsigned long long* pk = (unsigned long long*)(idx + ROWS);  // ROWS ull
  float* k2a = (float*)(pk + ROWS);                   // 73728
  float* k2b = k2a + K2A_FLOATS;                      // 6912
  float* chunkbuf = k2b + K2B_FLOATS + 64;

  int CH = 1;
  for (int c = 32; c >= 1; c >>= 1) {
    size_t need = ((size_t)FIX_FLOATS + (size_t)(H1_PER_N + Z_PER_N + H2_PER_N) * c) * 4;
    if (need <= ws_size) { CH = c; break; }
  }
  float* h1 = chunkbuf;                   // CH * 1,048,576  (reused as d2)
  float* z  = h1 + (size_t)H1_PER_N * CH; // CH * 262,144
  float* h2 = z + (size_t)Z_PER_N * CH;   // CH * 131,072    (reused as d1)

  k_init<<<ROWS / 256, 256, 0, stream>>>(lossA, pk);
  k_wtrans<<<(64 * 32 + 255) / 256, 256, 0, stream>>>(dec_w2, k2a, 64 * 32);
  k_wtrans<<<1, 256, 0, stream>>>(dec_w3, k2b, 3 * 64);

  float* out = (float*)d_out;

  for (int n0 = 0; n0 < Bn; n0 += CH) {
    int row0 = n0 * H2 * W2;
    k_conv1<<<CH * 128, 256, 0, stream>>>(x, enc_w1, enc_b1, h1, n0);
    k_conv2<<<CH * 32, 256, 0, stream>>>(h1, enc_w2, enc_b2, h2);
    k_conv3z<<<CH * 64, 256, 0, stream>>>(h2, enc_w3, enc_b3, z);
    // 4-way codebook split: grid = rowblocks(CH*16) x 4
    k_vq<<<CH * 16 * 4, 256, 0, stream>>>(z, cb, pk, row0);
    k_vqfin<<<CH * 16, 256, 0, stream>>>(z, cb, pk, idx, lossA, row0);
    k_dec1<<<CH * 64, 256, 0, stream>>>(idx, cb, dec_w1, dec_b1, h2, row0);
    // d1 (h2) -> d2 (h1): 32ch 64x64 -> 64ch 128x128, ReLU
    k_upconv2x<32, 64, 64, 4, true><<<CH * 16 * 2 * 2, 256, 0, stream>>>(
        h2, k2a, dec_b2, h1, 0);
    k_upfix<32, 64, 64, 16, true>
        <<<(CH * 4 * 508 + 255) / 256, 256, 0, stream>>>(
            h2, dec_w2, dec_b2, h1, CH, 0);
    // d2 (h1) -> recon: 64ch 128x128 -> 3ch 256x256, f32 out at offset 2
    k_upconv2x<64, 128, 3, 3, false><<<CH * 1 * 4 * 4, 256, 0, stream>>>(
        h1, k2b, dec_b3, out + 2, n0);
    k_upfix<64, 128, 3, 3, false>
        <<<(CH * 1 * 1020 + 255) / 256, 256, 0, stream>>>(
            h1, dec_w3, dec_b3, out + 2, CH, n0);
  }
  k_loss_final<<<1, 64, 0, stream>>>(lossA, out);
}

// Round 9
// 1348.203 us; speedup vs baseline: 1.5668x; 1.1278x over previous
//
#include <hip/hip_runtime.h>
#include <hip/hip_bf16.h>

static constexpr int Bn = 32;
static constexpr int Hin = 256, Win = 256;
static constexpr int C1 = 64, H1 = 128, W1 = 128;
static constexpr int C2 = 32, H2 = 64, W2 = 64;
static constexpr int Dd = 64;    // latent dim
static constexpr int Kc = 512;   // codebook entries
static constexpr int ROWS = Bn * H2 * W2;  // 131072

// ws layout (floats): lossA(64) | idx | pk | k2a | k2b | T1 | G | chunk
static constexpr int K2A_FLOATS = 64 * 32 * 36;   // 73728
static constexpr int K2B_FLOATS = 3 * 64 * 36;    // 6912
static constexpr int T1_FLOATS  = Kc * C2;        // 16384
static constexpr int G_FLOATS   = Kc * 9 * 64 * 4; // 1,179,648
static constexpr int FIX_FLOATS = 64 + ROWS + 2 * ROWS + K2A_FLOATS +
                                  K2B_FLOATS + T1_FLOATS + G_FLOATS + 64;
static constexpr int H1_PER_N = C1 * H1 * W1;    // 1,048,576
static constexpr int Z_PER_N  = H2 * W2 * Dd;    // 262,144
static constexpr int H2_PER_N = C2 * H2 * W2;    // 131,072

// ---------- init: zero loss accum, preset packed argmin keys ----------
__global__ __launch_bounds__(256) void k_init(
    float* __restrict__ lossA, unsigned long long* __restrict__ pk)
{
  int i = blockIdx.x * 256 + threadIdx.x;
  if (i < 64) lossA[i] = 0.f;
  pk[i] = 0xFFFFFFFFFFFFFFFFull;
}

// ---------- upsample-conv weight compose: K'[py,px] = Ay^T W Ax ----------
__global__ __launch_bounds__(256) void k_wtrans(
    const float* __restrict__ w, float* __restrict__ k2, int N)
{
  int i = blockIdx.x * 256 + threadIdx.x;
  if (i >= N) return;
  float W[3][3];
#pragma unroll
  for (int ty = 0; ty < 3; ++ty)
#pragma unroll
    for (int tx = 0; tx < 3; ++tx) W[ty][tx] = w[i * 9 + ty * 3 + tx];
  const float A[2][3][3] = {
      {{.75f, .25f, 0.f}, {.25f, .75f, 0.f}, {0.f, .75f, .25f}},
      {{.25f, .75f, 0.f}, {0.f, .75f, .25f}, {0.f, .25f, .75f}}};
#pragma unroll
  for (int py = 0; py < 2; ++py)
#pragma unroll
    for (int px = 0; px < 2; ++px)
#pragma unroll
      for (int a = 0; a < 3; ++a)
#pragma unroll
        for (int b = 0; b < 3; ++b) {
          float v = 0.f;
#pragma unroll
          for (int ty = 0; ty < 3; ++ty)
#pragma unroll
            for (int tx = 0; tx < 3; ++tx)
              v += W[ty][tx] * A[py][ty][a] * A[px][tx][b];
          k2[(size_t)i * 36 + (py * 2 + px) * 9 + a * 3 + b] = v;
        }
}

// ---------- T1[e][ci] = relu(dec_w1 . cb[e] + dec_b1) ----------
__global__ __launch_bounds__(256) void k_gtab1(
    const float* __restrict__ cb, const float* __restrict__ w1,
    const float* __restrict__ b1, float* __restrict__ T1)
{
  int g = blockIdx.x * 256 + threadIdx.x;  // 16384
  int e = g >> 5, ci = g & 31;
  const float* c = cb + e * Dd;
  const float* wr = w1 + ci * Dd;
  float a = 0.f;
#pragma unroll
  for (int d = 0; d < Dd; ++d) a += c[d] * wr[d];
  a += b1[ci];
  T1[g] = a > 0.f ? a : 0.f;
}

// ---------- G[e][ab][co][ph] = sum_ci k2a[(co*32+ci)*36+ph*9+ab]*T1[e][ci] ----------
__global__ __launch_bounds__(256) void k_gtab2(
    const float* __restrict__ k2a, const float* __restrict__ T1,
    float* __restrict__ G)
{
  int e = blockIdx.x;
  int tid = threadIdx.x;
  int co = tid >> 2, ph = tid & 3;
  __shared__ float sT[32];
  if (tid < 32) sT[tid] = T1[e * 32 + tid];
  __syncthreads();
  float acc[9];
#pragma unroll
  for (int ab = 0; ab < 9; ++ab) acc[ab] = 0.f;
  for (int ci = 0; ci < 32; ++ci) {
    float tv = sT[ci];
    const float* kp = k2a + (size_t)(co * 32 + ci) * 36 + ph * 9;
#pragma unroll
    for (int ab = 0; ab < 9; ++ab) acc[ab] += tv * kp[ab];
  }
#pragma unroll
  for (int ab = 0; ab < 9; ++ab)
    G[((size_t)e * 9 + ab) * 256 + tid] = acc[ab];
}

// ---------- enc conv1: 3->64, 3x3, s2, p1, ReLU ----------
__global__ __launch_bounds__(256) void k_conv1(
    const float* __restrict__ x, const float* __restrict__ w,
    const float* __restrict__ b, float* __restrict__ h1, int n0)
{
  int bid = blockIdx.x;
  int xt = bid & 1, yt = (bid >> 1) & 15, cc = (bid >> 5) & 3, n = bid >> 7;
  int X0 = xt * 64, Y0 = yt * 8, co0 = cc * 16;
  __shared__ float sIn[3][17][130];
  int tid = threadIdx.x;
  for (int i = tid; i < 3 * 17 * 130; i += 256) {
    int ci = i / (17 * 130);
    int rr = (i / 130) % 17;
    int ccx = i % 130;
    int gy = 2 * Y0 - 1 + rr, gx = 2 * X0 - 1 + ccx;
    float v = 0.f;
    if (gy >= 0 && gy < Hin && gx >= 0 && gx < Win)
      v = x[(((size_t)(n0 + n) * 3 + ci) * Hin + gy) * Win + gx];
    sIn[ci][rr][ccx] = v;
  }
  __syncthreads();
  int lx = tid & 63, ys = tid >> 6;
  float acc[16][2];
#pragma unroll
  for (int c = 0; c < 16; ++c) { acc[c][0] = 0.f; acc[c][1] = 0.f; }
#pragma unroll
  for (int ci = 0; ci < 3; ++ci)
#pragma unroll
    for (int ky = 0; ky < 3; ++ky)
#pragma unroll
      for (int kx = 0; kx < 3; ++kx) {
        float u0 = sIn[ci][2 * ys + ky][2 * lx + kx];
        float u1 = sIn[ci][2 * ys + 8 + ky][2 * lx + kx];
#pragma unroll
        for (int c = 0; c < 16; ++c) {
          float wv = w[((co0 + c) * 3 + ci) * 9 + ky * 3 + kx];
          acc[c][0] += u0 * wv;
          acc[c][1] += u1 * wv;
        }
      }
#pragma unroll
  for (int c = 0; c < 16; ++c) {
    float bv = b[co0 + c];
    float v0 = acc[c][0] + bv; v0 = v0 > 0.f ? v0 : 0.f;
    float v1 = acc[c][1] + bv; v1 = v1 > 0.f ? v1 : 0.f;
    h1[((n * C1 + co0 + c) * H1 + Y0 + ys) * W1 + X0 + lx] = v0;
    h1[((n * C1 + co0 + c) * H1 + Y0 + ys + 4) * W1 + X0 + lx] = v1;
  }
}

// ---------- enc conv2: 64->32, 3x3, s2, p1, ReLU ----------
__global__ __launch_bounds__(256) void k_conv2(
    const float* __restrict__ h1, const float* __restrict__ w,
    const float* __restrict__ b, float* __restrict__ h2)
{
  int bid = blockIdx.x;
  int yt = bid & 7, cg = (bid >> 3) & 3, n = bid >> 5;
  int Y0 = yt * 8, co0 = cg * 8;
  __shared__ float sIn[4][17][130];
  int tid = threadIdx.x;
  int lane = tid & 63, ci2 = tid >> 6;
  int lx = lane, ys = ci2;
  float acc[8][2];
#pragma unroll
  for (int c = 0; c < 8; ++c) { acc[c][0] = 0.f; acc[c][1] = 0.f; }
  for (int cb0 = 0; cb0 < C1; cb0 += 4) {
    __syncthreads();
    {
      const float* src = h1 + ((size_t)(n * C1 + cb0 + ci2)) * H1 * W1;
      float* dst = &sIn[ci2][0][0];
#pragma unroll 1
      for (int rr = 0; rr < 17; ++rr) {
        int gy = 2 * Y0 - 1 + rr;
        bool yok = (gy >= 0) & (gy < H1);
        const float* rowp = src + gy * W1;
        float v0 = (yok && lane > 0) ? rowp[lane - 1] : 0.f;
        float v1 = yok ? rowp[lane + 63] : 0.f;
        dst[rr * 130 + lane] = v0;
        dst[rr * 130 + 64 + lane] = v1;
        if (lane < 2) {
          float v2 = (yok && lane == 0) ? rowp[127] : 0.f;
          dst[rr * 130 + 128 + lane] = v2;
        }
      }
    }
    __syncthreads();
#pragma unroll
    for (int ci = 0; ci < 4; ++ci)
#pragma unroll
      for (int ky = 0; ky < 3; ++ky)
#pragma unroll
        for (int kx = 0; kx < 3; ++kx) {
          float u0 = sIn[ci][2 * ys + ky][2 * lx + kx];
          float u1 = sIn[ci][2 * ys + 8 + ky][2 * lx + kx];
#pragma unroll
          for (int c = 0; c < 8; ++c) {
            float wv = w[((co0 + c) * C1 + cb0 + ci) * 9 + ky * 3 + kx];
            acc[c][0] += u0 * wv;
            acc[c][1] += u1 * wv;
          }
        }
  }
#pragma unroll
  for (int c = 0; c < 8; ++c) {
    float bv = b[co0 + c];
    float v0 = acc[c][0] + bv; v0 = v0 > 0.f ? v0 : 0.f;
    float v1 = acc[c][1] + bv; v1 = v1 > 0.f ? v1 : 0.f;
    h2[((n * C2 + co0 + c) * H2 + Y0 + ys) * W2 + lx] = v0;
    h2[((n * C2 + co0 + c) * H2 + Y0 + ys + 4) * W2 + lx] = v1;
  }
}

// ---------- enc conv3 (1x1, 32->64) -> z in [row][64] ----------
__global__ __launch_bounds__(256) void k_conv3z(
    const float* __restrict__ h2, const float* __restrict__ w,
    const float* __restrict__ b, float* __restrict__ z)
{
  int bid = blockIdx.x;
  int y = bid & 63, n = bid >> 6;
  __shared__ float sH[C2][64];
  __shared__ float sW[Dd * 33];
  int tid = threadIdx.x;
  for (int i = tid; i < C2 * 64; i += 256) {
    int ci = i >> 6, xx = i & 63;
    sH[ci][xx] = h2[((n * C2 + ci) * H2 + y) * W2 + xx];
  }
  for (int i = tid; i < Dd * C2; i += 256) {
    int d = i >> 5, ci = i & 31;
    sW[d * 33 + ci] = w[i];
  }
  __syncthreads();
  int dg = tid & 3, lx = tid >> 2;
  float acc[16];
#pragma unroll
  for (int j = 0; j < 16; ++j) acc[j] = 0.f;
  for (int ci = 0; ci < C2; ++ci) {
    float u = sH[ci][lx];
#pragma unroll
    for (int j = 0; j < 16; ++j)
      acc[j] += u * sW[(dg * 16 + j) * 33 + ci];
  }
  int row = (n * H2 + y) * W2 + lx;
#pragma unroll
  for (int j = 0; j < 16; ++j)
    z[row * Dd + dg * 16 + j] = acc[j] + b[dg * 16 + j];
}

// ---------- VQ main: 4-way codebook split, packed atomicMin argmin ----------
__global__ __launch_bounds__(256) void k_vq(
    const float* __restrict__ z, const float* __restrict__ cbf,
    unsigned long long* __restrict__ pk, int row0)
{
  __shared__ float c2s[128];
  int bid = blockIdx.x;
  int sp = bid & 3, rb = bid >> 2;
  int c0 = sp * 128;
  int tid = threadIdx.x;
  if (tid < 128) {
    const float* cr = cbf + (size_t)(c0 + tid) * Dd;
    float s = 0.f;
#pragma unroll
    for (int d = 0; d < Dd; ++d) { float v = cr[d]; s += v * v; }
    c2s[tid] = s;
  }
  __syncthreads();
  int r = rb * 256 + tid;  // chunk-local row
  float4 zr[16];
  const float4* zp = (const float4*)(z + (size_t)r * Dd);
#pragma unroll
  for (int i = 0; i < 16; ++i) zr[i] = zp[i];
  float best = 1e30f; int bidx = c0;
  for (int c = 0; c < 128; ++c) {
    const float* __restrict__ cr = cbf + (size_t)(c0 + c) * Dd;
    float d0 = 0.f, d1 = 0.f, d2a = 0.f, d3 = 0.f;
#pragma unroll
    for (int i = 0; i < 16; ++i) {
      d0 += zr[i].x * cr[4 * i + 0];
      d1 += zr[i].y * cr[4 * i + 1];
      d2a += zr[i].z * cr[4 * i + 2];
      d3 += zr[i].w * cr[4 * i + 3];
    }
    float dot = (d0 + d1) + (d2a + d3);
    float dist = c2s[c] - 2.f * dot;
    if (dist < best) { best = dist; bidx = c0 + c; }
  }
  unsigned int u = __float_as_uint(best);
  unsigned int key32 = (u & 0x80000000u) ? ~u : (u | 0x80000000u);
  unsigned long long key =
      ((unsigned long long)key32 << 32) | (unsigned int)bidx;
  atomicMin(&pk[row0 + r], key);
}

// ---------- VQ merge: extract idx, accumulate loss ----------
__global__ __launch_bounds__(256) void k_vqfin(
    const float* __restrict__ z, const float* __restrict__ cbf,
    const unsigned long long* __restrict__ pk, int* __restrict__ idx,
    float* __restrict__ lossA, int row0)
{
  int r = blockIdx.x * 256 + threadIdx.x;  // chunk-local
  int gi = row0 + r;
  int bidx = (int)(pk[gi] & 0xFFFFFFFFull);
  idx[gi] = bidx;
  const float4* zp = (const float4*)(z + (size_t)r * Dd);
  const float4* cr = (const float4*)(cbf + (size_t)bidx * Dd);
  float ls = 0.f;
#pragma unroll
  for (int i = 0; i < 16; ++i) {
    float4 zv = zp[i], cv = cr[i];
    float e0 = zv.x - cv.x, e1 = zv.y - cv.y;
    float e2 = zv.z - cv.z, e3 = zv.w - cv.w;
    ls += e0 * e0 + e1 * e1 + e2 * e2 + e3 * e3;
  }
#pragma unroll
  for (int off = 32; off > 0; off >>= 1) ls += __shfl_down(ls, off);
  if ((threadIdx.x & 63) == 0) atomicAdd(lossA, ls);
}

__global__ void k_loss_final(const float* __restrict__ a, float* __restrict__ out)
{
  if (threadIdx.x == 0) {
    float l = a[0] / (float)(ROWS * Dd);
    out[0] = l;
    out[1] = l;
  }
}

// ---------- d1 gather: d1[n][ci][y][x] = T1[idx][ci] (for border fixup) ----------
__global__ __launch_bounds__(256) void k_d1g(
    const int* __restrict__ idx, const float* __restrict__ T1,
    float* __restrict__ d1, int row0)
{
  int p = blockIdx.x * 256 + threadIdx.x;  // chunk-local pixel
  int e = idx[row0 + p];
  int n = p >> 12, px = p & 4095;
  const float4* t = (const float4*)(T1 + e * 32);
#pragma unroll
  for (int i = 0; i < 8; ++i) {
    float4 v = t[i];
    float* base = d1 + ((size_t)(n * C2 + i * 4) << 12) + px;
    base[0] = v.x; base[4096] = v.y; base[8192] = v.z; base[12288] = v.w;
  }
}

// ---------- d2 interior via G-table gather: 9 gathers + 9 adds per out ----------
// grid: n x cog(8) x ty(4) x tx(4); thread = one low-res px, 8 co x 4 ph.
__global__ __launch_bounds__(256) void k_upg(
    const int* __restrict__ idx, const float* __restrict__ G,
    const float* __restrict__ bias, float* __restrict__ O, int row0)
{
  int bid = blockIdx.x;
  int tx = bid & 3; bid >>= 2;
  int ty = bid & 3; bid >>= 2;
  int cog = bid & 7; bid >>= 3;
  int n = bid;
  int Y0 = ty * 16, X0 = tx * 16, co0 = cog * 8;
  __shared__ int sIdx[18 * 18];
  int tid = threadIdx.x;
  int base = row0 + (n << 12);
  for (int i = tid; i < 324; i += 256) {
    int r = i / 18, c = i % 18;
    int gy = Y0 - 1 + r; gy = gy < 0 ? 0 : (gy > 63 ? 63 : gy);
    int gx = X0 - 1 + c; gx = gx < 0 ? 0 : (gx > 63 ? 63 : gx);
    sIdx[i] = idx[base + gy * 64 + gx];
  }
  __syncthreads();
  int xx = tid & 15, yy = tid >> 4;
  float4 acc[8];
#pragma unroll
  for (int j = 0; j < 8; ++j) acc[j] = make_float4(0.f, 0.f, 0.f, 0.f);
#pragma unroll
  for (int a = 0; a < 3; ++a)
#pragma unroll
    for (int b = 0; b < 3; ++b) {
      int e = sIdx[(yy + a) * 18 + xx + b];
      const float4* gp =
          (const float4*)(G + ((size_t)(e * 9 + a * 3 + b) * 256) + co0 * 4);
#pragma unroll
      for (int j = 0; j < 8; ++j) {
        float4 gv = gp[j];
        acc[j].x += gv.x; acc[j].y += gv.y;
        acc[j].z += gv.z; acc[j].w += gv.w;
      }
    }
  int oy = 2 * (Y0 + yy), ox = 2 * (X0 + xx);
#pragma unroll
  for (int j = 0; j < 8; ++j) {
    int co = co0 + j;
    float bv = bias[co];
    float2 r0, r1;
    r0.x = acc[j].x + bv; r0.y = acc[j].y + bv;
    r1.x = acc[j].z + bv; r1.y = acc[j].w + bv;
    r0.x = r0.x > 0.f ? r0.x : 0.f; r0.y = r0.y > 0.f ? r0.y : 0.f;
    r1.x = r1.x > 0.f ? r1.x : 0.f; r1.y = r1.y > 0.f ? r1.y : 0.f;
    size_t o = ((size_t)(n * 64 + co) * 128 + oy) * 128 + ox;
    *(float2*)&O[o] = r0;
    *(float2*)&O[o + 128] = r1;
  }
}

// ---------- composed upsample2x+conv3x3 (still used for 64->3) ----------
template <int Ci, int Hi, int Co, int COCH, bool RELU>
__global__ __launch_bounds__(256) void k_upconv2x(
    const float* __restrict__ I, const float* __restrict__ k2,
    const float* __restrict__ bias, float* __restrict__ O, int n0)
{
  constexpr int TT = Hi / 32, NCG = Co / COCH, Ho = 2 * Hi, Wo = 2 * Hi;
  int bid = blockIdx.x;
  int tx = bid % TT; bid /= TT;
  int ty = bid % TT; bid /= TT;
  int cg = bid % NCG; bid /= NCG;
  int n = bid;
  int Y0 = ty * 32, X0 = tx * 32;
  __shared__ float sI[4][34 * 35];
  int tid = threadIdx.x;
  int lx = tid & 15, ly = tid >> 4;
  float4 acc[COCH][2][2];
#pragma unroll
  for (int j = 0; j < COCH; ++j)
#pragma unroll
    for (int a = 0; a < 2; ++a)
#pragma unroll
      for (int b = 0; b < 2; ++b) acc[j][a][b] = make_float4(0.f, 0.f, 0.f, 0.f);
  const float* kbase = k2 + (size_t)cg * COCH * Ci * 36;
  for (int c0 = 0; c0 < Ci; c0 += 4) {
    __syncthreads();
    for (int i = tid; i < 4 * 34 * 34; i += 256) {
      int s = i / 1156, r2 = i % 1156;
      int rr = r2 / 34, cc2 = r2 % 34;
      int gy = Y0 - 1 + rr; gy = gy < 0 ? 0 : (gy > Hi - 1 ? Hi - 1 : gy);
      int gx = X0 - 1 + cc2; gx = gx < 0 ? 0 : (gx > Hi - 1 ? Hi - 1 : gx);
      sI[s][rr * 35 + cc2] = I[((size_t)n * Ci + c0 + s) * Hi * Hi + gy * Hi + gx];
    }
    __syncthreads();
#pragma unroll
    for (int s = 0; s < 4; ++s) {
      float t[4][4];
#pragma unroll
      for (int r = 0; r < 4; ++r)
#pragma unroll
        for (int c = 0; c < 4; ++c)
          t[r][c] = sI[s][(2 * ly + r) * 35 + 2 * lx + c];
#pragma unroll
      for (int j = 0; j < COCH; ++j) {
        const float* kj = kbase + ((size_t)j * Ci + c0 + s) * 36;
#pragma unroll
        for (int a = 0; a < 3; ++a)
#pragma unroll
          for (int b = 0; b < 3; ++b) {
            float w00 = kj[a * 3 + b];
            float w01 = kj[9 + a * 3 + b];
            float w10 = kj[18 + a * 3 + b];
            float w11 = kj[27 + a * 3 + b];
#pragma unroll
            for (int pyy = 0; pyy < 2; ++pyy) {
              float i0 = t[pyy + a][b];
              float i1 = t[pyy + a][b + 1];
              acc[j][pyy][0].x += i0 * w00;
              acc[j][pyy][0].y += i0 * w01;
              acc[j][pyy][0].z += i1 * w00;
              acc[j][pyy][0].w += i1 * w01;
              acc[j][pyy][1].x += i0 * w10;
              acc[j][pyy][1].y += i0 * w11;
              acc[j][pyy][1].z += i1 * w10;
              acc[j][pyy][1].w += i1 * w11;
            }
          }
      }
    }
  }
  int ox = 2 * X0 + 4 * lx;
#pragma unroll
  for (int j = 0; j < COCH; ++j) {
    int co = cg * COCH + j;
    float bv = bias[co];
#pragma unroll
    for (int pyy = 0; pyy < 2; ++pyy) {
      int oy0 = 2 * (Y0 + 2 * ly + pyy);
#pragma unroll
      for (int py = 0; py < 2; ++py) {
        float4 v = acc[j][pyy][py];
        v.x += bv; v.y += bv; v.z += bv; v.w += bv;
        if (RELU) {
          v.x = v.x > 0.f ? v.x : 0.f;
          v.y = v.y > 0.f ? v.y : 0.f;
          v.z = v.z > 0.f ? v.z : 0.f;
          v.w = v.w > 0.f ? v.w : 0.f;
        }
        size_t off = (((size_t)(0 + n) * Co + co) * Ho + oy0 + py) * Wo + ox;
        off += (size_t)n0 * Co * Ho * Wo;
        *(float4*)&O[off] = v;
      }
    }
  }
}

// ---------- exact direct computation of the output border ring ----------
template <int Ci, int Hi, int Co, int CG, bool RELU>
__global__ __launch_bounds__(256) void k_upfix(
    const float* __restrict__ I, const float* __restrict__ w,
    const float* __restrict__ bias, float* __restrict__ O, int CHn, int n0)
{
  constexpr int Ho = 2 * Hi, Wo = 2 * Hi;
  constexpr int RING = 2 * (Ho + Wo) - 4;
  constexpr int NCG = Co / CG;
  int gi = blockIdx.x * 256 + threadIdx.x;
  if (gi >= CHn * NCG * RING) return;
  int p = gi % RING;
  int cgrp = (gi / RING) % NCG;
  int n = gi / (RING * NCG);
  int u, v;
  if (p < Wo)            { u = 0;       v = p; }
  else if (p < 2 * Wo)   { u = Ho - 1;  v = p - Wo; }
  else { int q = p - 2 * Wo; u = 1 + (q >> 1); v = (q & 1) ? (Wo - 1) : 0; }
  float acc[CG];
#pragma unroll
  for (int j = 0; j < CG; ++j) acc[j] = 0.f;
  for (int ci = 0; ci < Ci; ++ci) {
    const float* Ip = I + ((size_t)n * Ci + ci) * Hi * Hi;
    float U[9];
#pragma unroll
    for (int dy = 0; dy < 3; ++dy)
#pragma unroll
      for (int dx = 0; dx < 3; ++dx) {
        int vy = u - 1 + dy, vx = v - 1 + dx;
        float val = 0.f;
        if (vy >= 0 && vy < Ho && vx >= 0 && vx < Wo) {
          int ky0, ky1, kx0, kx1; float ay0, ax0;
          if (vy & 1) { ky0 = vy >> 1; ky1 = ky0 + 1; ay0 = .75f; }
          else        { ky1 = vy >> 1; ky0 = ky1 - 1; ay0 = .25f; }
          if (vx & 1) { kx0 = vx >> 1; kx1 = kx0 + 1; ax0 = .75f; }
          else        { kx1 = vx >> 1; kx0 = kx1 - 1; ax0 = .25f; }
          ky0 = ky0 < 0 ? 0 : (ky0 > Hi - 1 ? Hi - 1 : ky0);
          ky1 = ky1 < 0 ? 0 : (ky1 > Hi - 1 ? Hi - 1 : ky1);
          kx0 = kx0 < 0 ? 0 : (kx0 > Hi - 1 ? Hi - 1 : kx0);
          kx1 = kx1 < 0 ? 0 : (kx1 > Hi - 1 ? Hi - 1 : kx1);
          float ay1 = 1.f - ay0, ax1 = 1.f - ax0;
          float r0 = ax0 * Ip[ky0 * Hi + kx0] + ax1 * Ip[ky0 * Hi + kx1];
          float r1 = ax0 * Ip[ky1 * Hi + kx0] + ax1 * Ip[ky1 * Hi + kx1];
          val = ay0 * r0 + ay1 * r1;
        }
        U[dy * 3 + dx] = val;
      }
#pragma unroll
    for (int j = 0; j < CG; ++j) {
      const float* wp = w + ((size_t)(cgrp * CG + j) * Ci + ci) * 9;
#pragma unroll
      for (int tp = 0; tp < 9; ++tp) acc[j] += U[tp] * wp[tp];
    }
  }
#pragma unroll
  for (int j = 0; j < CG; ++j) {
    int co = cgrp * CG + j;
    float val = acc[j] + bias[co];
    if (RELU) val = val > 0.f ? val : 0.f;
    O[((size_t)((n0 + n) * Co + co) * Ho + u) * Wo + v] = val;
  }
}

extern "C" void kernel_launch(void* const* d_in, const int* in_sizes, int n_in,
                              void* d_out, int out_size, void* d_ws, size_t ws_size,
                              hipStream_t stream)
{
  const float* x      = (const float*)d_in[0];
  const float* cb     = (const float*)d_in[1];
  const float* enc_w1 = (const float*)d_in[2];
  const float* enc_b1 = (const float*)d_in[3];
  const float* enc_w2 = (const float*)d_in[4];
  const float* enc_b2 = (const float*)d_in[5];
  const float* enc_w3 = (const float*)d_in[6];
  const float* enc_b3 = (const float*)d_in[7];
  const float* dec_w1 = (const float*)d_in[8];
  const float* dec_b1 = (const float*)d_in[9];
  const float* dec_w2 = (const float*)d_in[10];
  const float* dec_b2 = (const float*)d_in[11];
  const float* dec_w3 = (const float*)d_in[12];
  const float* dec_b3 = (const float*)d_in[13];

  float* ws = (float*)d_ws;
  float* lossA = ws;                                  // 64
  int* idx = (int*)(lossA + 64);                      // ROWS ints
  unsigned long long* pk = (unsigned long long*)(idx + ROWS);  // ROWS ull
  float* k2a = (float*)(pk + ROWS);                   // 73728
  float* k2b = k2a + K2A_FLOATS;                      // 6912
  float* T1  = k2b + K2B_FLOATS;                      // 16384
  float* G   = T1 + T1_FLOATS;                        // 1,179,648
  float* chunkbuf = G + G_FLOATS + 64;

  int CH = 1;
  for (int c = 32; c >= 1; c >>= 1) {
    size_t need = ((size_t)FIX_FLOATS + (size_t)(H1_PER_N + Z_PER_N + H2_PER_N) * c) * 4;
    if (need <= ws_size) { CH = c; break; }
  }
  float* h1 = chunkbuf;                   // CH * 1,048,576  (reused as d2)
  float* z  = h1 + (size_t)H1_PER_N * CH; // CH * 262,144
  float* h2 = z + (size_t)Z_PER_N * CH;   // CH * 131,072    (reused as d1)

  k_init<<<ROWS / 256, 256, 0, stream>>>(lossA, pk);
  k_wtrans<<<(64 * 32 + 255) / 256, 256, 0, stream>>>(dec_w2, k2a, 64 * 32);
  k_wtrans<<<1, 256, 0, stream>>>(dec_w3, k2b, 3 * 64);
  k_gtab1<<<64, 256, 0, stream>>>(cb, dec_w1, dec_b1, T1);
  k_gtab2<<<Kc, 256, 0, stream>>>(k2a, T1, G);

  float* out = (float*)d_out;

  for (int n0 = 0; n0 < Bn; n0 += CH) {
    int row0 = n0 * H2 * W2;
    k_conv1<<<CH * 128, 256, 0, stream>>>(x, enc_w1, enc_b1, h1, n0);
    k_conv2<<<CH * 32, 256, 0, stream>>>(h1, enc_w2, enc_b2, h2);
    k_conv3z<<<CH * 64, 256, 0, stream>>>(h2, enc_w3, enc_b3, z);
    k_vq<<<CH * 16 * 4, 256, 0, stream>>>(z, cb, pk, row0);
    k_vqfin<<<CH * 16, 256, 0, stream>>>(z, cb, pk, idx, lossA, row0);
    // d1 via T1 gather (needed only for the border fixup pass)
    k_d1g<<<CH * 16, 256, 0, stream>>>(idx, T1, h2, row0);
    // d2 interior via G gather: grid n x cog(8) x ty(4) x tx(4)
    k_upg<<<CH * 8 * 16, 256, 0, stream>>>(idx, G, dec_b2, h1, row0);
    k_upfix<32, 64, 64, 16, true>
        <<<(CH * 4 * 508 + 255) / 256, 256, 0, stream>>>(
            h2, dec_w2, dec_b2, h1, CH, 0);
    // d2 (h1) -> recon: 64ch 128x128 -> 3ch 256x256, f32 out at offset 2
    k_upconv2x<64, 128, 3, 3, false><<<CH * 1 * 4 * 4, 256, 0, stream>>>(
        h1, k2b, dec_b3, out + 2, n0);
    k_upfix<64, 128, 3, 3, false>
        <<<(CH * 1 * 1020 + 255) / 256, 256, 0, stream>>>(
            h1, dec_w3, dec_b3, out + 2, CH, n0);
  }
  k_loss_final<<<1, 64, 0, stream>>>(lossA, out);
}

// Round 10
// 1112.063 us; speedup vs baseline: 1.8995x; 1.2123x over previous
//
#include <hip/hip_runtime.h>
#include <hip/hip_bf16.h>

static constexpr int Bn = 32;
static constexpr int Hin = 256, Win = 256;
static constexpr int C1 = 64, H1 = 128, W1 = 128;
static constexpr int C2 = 32, H2 = 64, W2 = 64;
static constexpr int Dd = 64;    // latent dim
static constexpr int Kc = 512;   // codebook entries
static constexpr int ROWS = Bn * H2 * W2;  // 131072

// ws layout (floats): lossA(64) | idx | pk | k2a | k2b | T1 | G | chunk
static constexpr int K2A_FLOATS = 64 * 32 * 36;   // 73728
static constexpr int K2B_FLOATS = 3 * 64 * 36;    // 6912
static constexpr int T1_FLOATS  = Kc * C2;        // 16384
static constexpr int G_FLOATS   = Kc * 9 * 64 * 4; // 1,179,648
static constexpr int FIX_FLOATS = 64 + ROWS + 2 * ROWS + K2A_FLOATS +
                                  K2B_FLOATS + T1_FLOATS + G_FLOATS + 64;
static constexpr int H1_PER_N = C1 * H1 * W1;    // 1,048,576
static constexpr int Z_PER_N  = H2 * W2 * Dd;    // 262,144
static constexpr int H2_PER_N = C2 * H2 * W2;    // 131,072

// ---------- init ----------
__global__ __launch_bounds__(256) void k_init(
    float* __restrict__ lossA, unsigned long long* __restrict__ pk)
{
  int i = blockIdx.x * 256 + threadIdx.x;
  if (i < 64) lossA[i] = 0.f;
  pk[i] = 0xFFFFFFFFFFFFFFFFull;
}

// ---------- upsample-conv weight compose: K'[py,px] = Ay^T W Ax ----------
__global__ __launch_bounds__(256) void k_wtrans(
    const float* __restrict__ w, float* __restrict__ k2, int N)
{
  int i = blockIdx.x * 256 + threadIdx.x;
  if (i >= N) return;
  float W[3][3];
#pragma unroll
  for (int ty = 0; ty < 3; ++ty)
#pragma unroll
    for (int tx = 0; tx < 3; ++tx) W[ty][tx] = w[i * 9 + ty * 3 + tx];
  const float A[2][3][3] = {
      {{.75f, .25f, 0.f}, {.25f, .75f, 0.f}, {0.f, .75f, .25f}},
      {{.25f, .75f, 0.f}, {0.f, .75f, .25f}, {0.f, .25f, .75f}}};
#pragma unroll
  for (int py = 0; py < 2; ++py)
#pragma unroll
    for (int px = 0; px < 2; ++px)
#pragma unroll
      for (int a = 0; a < 3; ++a)
#pragma unroll
        for (int b = 0; b < 3; ++b) {
          float v = 0.f;
#pragma unroll
          for (int ty = 0; ty < 3; ++ty)
#pragma unroll
            for (int tx = 0; tx < 3; ++tx)
              v += W[ty][tx] * A[py][ty][a] * A[px][tx][b];
          k2[(size_t)i * 36 + (py * 2 + px) * 9 + a * 3 + b] = v;
        }
}

// ---------- T1[e][ci] = relu(dec_w1 . cb[e] + dec_b1) ----------
__global__ __launch_bounds__(256) void k_gtab1(
    const float* __restrict__ cb, const float* __restrict__ w1,
    const float* __restrict__ b1, float* __restrict__ T1)
{
  int g = blockIdx.x * 256 + threadIdx.x;  // 16384
  int e = g >> 5, ci = g & 31;
  const float* c = cb + e * Dd;
  const float* wr = w1 + ci * Dd;
  float a = 0.f;
#pragma unroll
  for (int d = 0; d < Dd; ++d) a += c[d] * wr[d];
  a += b1[ci];
  T1[g] = a > 0.f ? a : 0.f;
}

// ---------- G[e][ab][co][ph] ----------
__global__ __launch_bounds__(256) void k_gtab2(
    const float* __restrict__ k2a, const float* __restrict__ T1,
    float* __restrict__ G)
{
  int e = blockIdx.x;
  int tid = threadIdx.x;
  int co = tid >> 2, ph = tid & 3;
  __shared__ float sT[32];
  if (tid < 32) sT[tid] = T1[e * 32 + tid];
  __syncthreads();
  float acc[9];
#pragma unroll
  for (int ab = 0; ab < 9; ++ab) acc[ab] = 0.f;
  for (int ci = 0; ci < 32; ++ci) {
    float tv = sT[ci];
    const float* kp = k2a + (size_t)(co * 32 + ci) * 36 + ph * 9;
#pragma unroll
    for (int ab = 0; ab < 9; ++ab) acc[ab] += tv * kp[ab];
  }
#pragma unroll
  for (int ab = 0; ab < 9; ++ab)
    G[((size_t)e * 9 + ab) * 256 + tid] = acc[ab];
}

// ---------- enc conv1: 3->64, 3x3, s2, p1, ReLU ----------
__global__ __launch_bounds__(256) void k_conv1(
    const float* __restrict__ x, const float* __restrict__ w,
    const float* __restrict__ b, float* __restrict__ h1, int n0)
{
  int bid = blockIdx.x;
  int xt = bid & 1, yt = (bid >> 1) & 15, cc = (bid >> 5) & 3, n = bid >> 7;
  int X0 = xt * 64, Y0 = yt * 8, co0 = cc * 16;
  __shared__ float sIn[3][17][130];
  int tid = threadIdx.x;
  for (int i = tid; i < 3 * 17 * 130; i += 256) {
    int ci = i / (17 * 130);
    int rr = (i / 130) % 17;
    int ccx = i % 130;
    int gy = 2 * Y0 - 1 + rr, gx = 2 * X0 - 1 + ccx;
    float v = 0.f;
    if (gy >= 0 && gy < Hin && gx >= 0 && gx < Win)
      v = x[(((size_t)(n0 + n) * 3 + ci) * Hin + gy) * Win + gx];
    sIn[ci][rr][ccx] = v;
  }
  __syncthreads();
  int lx = tid & 63, ys = tid >> 6;
  float acc[16][2];
#pragma unroll
  for (int c = 0; c < 16; ++c) { acc[c][0] = 0.f; acc[c][1] = 0.f; }
#pragma unroll
  for (int ci = 0; ci < 3; ++ci)
#pragma unroll
    for (int ky = 0; ky < 3; ++ky)
#pragma unroll
      for (int kx = 0; kx < 3; ++kx) {
        float u0 = sIn[ci][2 * ys + ky][2 * lx + kx];
        float u1 = sIn[ci][2 * ys + 8 + ky][2 * lx + kx];
#pragma unroll
        for (int c = 0; c < 16; ++c) {
          float wv = w[((co0 + c) * 3 + ci) * 9 + ky * 3 + kx];
          acc[c][0] += u0 * wv;
          acc[c][1] += u1 * wv;
        }
      }
#pragma unroll
  for (int c = 0; c < 16; ++c) {
    float bv = b[co0 + c];
    float v0 = acc[c][0] + bv; v0 = v0 > 0.f ? v0 : 0.f;
    float v1 = acc[c][1] + bv; v1 = v1 > 0.f ? v1 : 0.f;
    h1[((n * C1 + co0 + c) * H1 + Y0 + ys) * W1 + X0 + lx] = v0;
    h1[((n * C1 + co0 + c) * H1 + Y0 + ys + 4) * W1 + X0 + lx] = v1;
  }
}

// ---------- enc conv2: 64->32, 3x3, s2, p1, ReLU ----------
__global__ __launch_bounds__(256) void k_conv2(
    const float* __restrict__ h1, const float* __restrict__ w,
    const float* __restrict__ b, float* __restrict__ h2)
{
  int bid = blockIdx.x;
  int yt = bid & 7, cg = (bid >> 3) & 3, n = bid >> 5;
  int Y0 = yt * 8, co0 = cg * 8;
  __shared__ float sIn[4][17][130];
  int tid = threadIdx.x;
  int lane = tid & 63, ci2 = tid >> 6;
  int lx = lane, ys = ci2;
  float acc[8][2];
#pragma unroll
  for (int c = 0; c < 8; ++c) { acc[c][0] = 0.f; acc[c][1] = 0.f; }
  for (int cb0 = 0; cb0 < C1; cb0 += 4) {
    __syncthreads();
    {
      const float* src = h1 + ((size_t)(n * C1 + cb0 + ci2)) * H1 * W1;
      float* dst = &sIn[ci2][0][0];
#pragma unroll 1
      for (int rr = 0; rr < 17; ++rr) {
        int gy = 2 * Y0 - 1 + rr;
        bool yok = (gy >= 0) & (gy < H1);
        const float* rowp = src + gy * W1;
        float v0 = (yok && lane > 0) ? rowp[lane - 1] : 0.f;
        float v1 = yok ? rowp[lane + 63] : 0.f;
        dst[rr * 130 + lane] = v0;
        dst[rr * 130 + 64 + lane] = v1;
        if (lane < 2) {
          float v2 = (yok && lane == 0) ? rowp[127] : 0.f;
          dst[rr * 130 + 128 + lane] = v2;
        }
      }
    }
    __syncthreads();
#pragma unroll
    for (int ci = 0; ci < 4; ++ci)
#pragma unroll
      for (int ky = 0; ky < 3; ++ky)
#pragma unroll
        for (int kx = 0; kx < 3; ++kx) {
          float u0 = sIn[ci][2 * ys + ky][2 * lx + kx];
          float u1 = sIn[ci][2 * ys + 8 + ky][2 * lx + kx];
#pragma unroll
          for (int c = 0; c < 8; ++c) {
            float wv = w[((co0 + c) * C1 + cb0 + ci) * 9 + ky * 3 + kx];
            acc[c][0] += u0 * wv;
            acc[c][1] += u1 * wv;
          }
        }
  }
#pragma unroll
  for (int c = 0; c < 8; ++c) {
    float bv = b[co0 + c];
    float v0 = acc[c][0] + bv; v0 = v0 > 0.f ? v0 : 0.f;
    float v1 = acc[c][1] + bv; v1 = v1 > 0.f ? v1 : 0.f;
    h2[((n * C2 + co0 + c) * H2 + Y0 + ys) * W2 + lx] = v0;
    h2[((n * C2 + co0 + c) * H2 + Y0 + ys + 4) * W2 + lx] = v1;
  }
}

// ---------- enc conv3 (1x1, 32->64) -> z ----------
__global__ __launch_bounds__(256) void k_conv3z(
    const float* __restrict__ h2, const float* __restrict__ w,
    const float* __restrict__ b, float* __restrict__ z)
{
  int bid = blockIdx.x;
  int y = bid & 63, n = bid >> 6;
  __shared__ float sH[C2][64];
  __shared__ float sW[Dd * 33];
  int tid = threadIdx.x;
  for (int i = tid; i < C2 * 64; i += 256) {
    int ci = i >> 6, xx = i & 63;
    sH[ci][xx] = h2[((n * C2 + ci) * H2 + y) * W2 + xx];
  }
  for (int i = tid; i < Dd * C2; i += 256) {
    int d = i >> 5, ci = i & 31;
    sW[d * 33 + ci] = w[i];
  }
  __syncthreads();
  int dg = tid & 3, lx = tid >> 2;
  float acc[16];
#pragma unroll
  for (int j = 0; j < 16; ++j) acc[j] = 0.f;
  for (int ci = 0; ci < C2; ++ci) {
    float u = sH[ci][lx];
#pragma unroll
    for (int j = 0; j < 16; ++j)
      acc[j] += u * sW[(dg * 16 + j) * 33 + ci];
  }
  int row = (n * H2 + y) * W2 + lx;
#pragma unroll
  for (int j = 0; j < 16; ++j)
    z[row * Dd + dg * 16 + j] = acc[j] + b[dg * 16 + j];
}

// ---------- VQ main ----------
__global__ __launch_bounds__(256) void k_vq(
    const float* __restrict__ z, const float* __restrict__ cbf,
    unsigned long long* __restrict__ pk, int row0)
{
  __shared__ float c2s[128];
  int bid = blockIdx.x;
  int sp = bid & 3, rb = bid >> 2;
  int c0 = sp * 128;
  int tid = threadIdx.x;
  if (tid < 128) {
    const float* cr = cbf + (size_t)(c0 + tid) * Dd;
    float s = 0.f;
#pragma unroll
    for (int d = 0; d < Dd; ++d) { float v = cr[d]; s += v * v; }
    c2s[tid] = s;
  }
  __syncthreads();
  int r = rb * 256 + tid;
  float4 zr[16];
  const float4* zp = (const float4*)(z + (size_t)r * Dd);
#pragma unroll
  for (int i = 0; i < 16; ++i) zr[i] = zp[i];
  float best = 1e30f; int bidx = c0;
  for (int c = 0; c < 128; ++c) {
    const float* __restrict__ cr = cbf + (size_t)(c0 + c) * Dd;
    float d0 = 0.f, d1 = 0.f, d2a = 0.f, d3 = 0.f;
#pragma unroll
    for (int i = 0; i < 16; ++i) {
      d0 += zr[i].x * cr[4 * i + 0];
      d1 += zr[i].y * cr[4 * i + 1];
      d2a += zr[i].z * cr[4 * i + 2];
      d3 += zr[i].w * cr[4 * i + 3];
    }
    float dot = (d0 + d1) + (d2a + d3);
    float dist = c2s[c] - 2.f * dot;
    if (dist < best) { best = dist; bidx = c0 + c; }
  }
  unsigned int u = __float_as_uint(best);
  unsigned int key32 = (u & 0x80000000u) ? ~u : (u | 0x80000000u);
  unsigned long long key =
      ((unsigned long long)key32 << 32) | (unsigned int)bidx;
  atomicMin(&pk[row0 + r], key);
}

// ---------- VQ merge ----------
__global__ __launch_bounds__(256) void k_vqfin(
    const float* __restrict__ z, const float* __restrict__ cbf,
    const unsigned long long* __restrict__ pk, int* __restrict__ idx,
    float* __restrict__ lossA, int row0)
{
  int r = blockIdx.x * 256 + threadIdx.x;
  int gi = row0 + r;
  int bidx = (int)(pk[gi] & 0xFFFFFFFFull);
  idx[gi] = bidx;
  const float4* zp = (const float4*)(z + (size_t)r * Dd);
  const float4* cr = (const float4*)(cbf + (size_t)bidx * Dd);
  float ls = 0.f;
#pragma unroll
  for (int i = 0; i < 16; ++i) {
    float4 zv = zp[i], cv = cr[i];
    float e0 = zv.x - cv.x, e1 = zv.y - cv.y;
    float e2 = zv.z - cv.z, e3 = zv.w - cv.w;
    ls += e0 * e0 + e1 * e1 + e2 * e2 + e3 * e3;
  }
#pragma unroll
  for (int off = 32; off > 0; off >>= 1) ls += __shfl_down(ls, off);
  if ((threadIdx.x & 63) == 0) atomicAdd(lossA, ls);
}

__global__ void k_loss_final(const float* __restrict__ a, float* __restrict__ out)
{
  if (threadIdx.x == 0) {
    float l = a[0] / (float)(ROWS * Dd);
    out[0] = l;
    out[1] = l;
  }
}

// ---------- d2 interior via G-table gather ----------
__global__ __launch_bounds__(256) void k_upg(
    const int* __restrict__ idx, const float* __restrict__ G,
    const float* __restrict__ bias, float* __restrict__ O, int row0)
{
  int bid = blockIdx.x;
  int tx = bid & 3; bid >>= 2;
  int ty = bid & 3; bid >>= 2;
  int cog = bid & 7; bid >>= 3;
  int n = bid;
  int Y0 = ty * 16, X0 = tx * 16, co0 = cog * 8;
  __shared__ int sIdx[18 * 18];
  int tid = threadIdx.x;
  int base = row0 + (n << 12);
  for (int i = tid; i < 324; i += 256) {
    int r = i / 18, c = i % 18;
    int gy = Y0 - 1 + r; gy = gy < 0 ? 0 : (gy > 63 ? 63 : gy);
    int gx = X0 - 1 + c; gx = gx < 0 ? 0 : (gx > 63 ? 63 : gx);
    sIdx[i] = idx[base + gy * 64 + gx];
  }
  __syncthreads();
  int xx = tid & 15, yy = tid >> 4;
  float4 acc[8];
#pragma unroll
  for (int j = 0; j < 8; ++j) acc[j] = make_float4(0.f, 0.f, 0.f, 0.f);
#pragma unroll
  for (int a = 0; a < 3; ++a)
#pragma unroll
    for (int b = 0; b < 3; ++b) {
      int e = sIdx[(yy + a) * 18 + xx + b];
      const float4* gp =
          (const float4*)(G + ((size_t)(e * 9 + a * 3 + b) * 256) + co0 * 4);
#pragma unroll
      for (int j = 0; j < 8; ++j) {
        float4 gv = gp[j];
        acc[j].x += gv.x; acc[j].y += gv.y;
        acc[j].z += gv.z; acc[j].w += gv.w;
      }
    }
  int oy = 2 * (Y0 + yy), ox = 2 * (X0 + xx);
#pragma unroll
  for (int j = 0; j < 8; ++j) {
    int co = co0 + j;
    float bv = bias[co];
    float2 r0, r1;
    r0.x = acc[j].x + bv; r0.y = acc[j].y + bv;
    r1.x = acc[j].z + bv; r1.y = acc[j].w + bv;
    r0.x = r0.x > 0.f ? r0.x : 0.f; r0.y = r0.y > 0.f ? r0.y : 0.f;
    r1.x = r1.x > 0.f ? r1.x : 0.f; r1.y = r1.y > 0.f ? r1.y : 0.f;
    size_t o = ((size_t)(n * 64 + co) * 128 + oy) * 128 + ox;
    *(float2*)&O[o] = r0;
    *(float2*)&O[o + 128] = r1;
  }
}

// ---------- exact d2 border ring via T1-gathered LDS strips ----------
// sides: 0 top(u=0), 1 bottom(u=127), 2 left(v=0,u 1..126), 3 right(v=127).
// grid: ((n*4 + side)*2 + ch) ; 256 thr = 128 px x 2 co-quarters.
__global__ __launch_bounds__(256) void k_border_a(
    const int* __restrict__ idx, const float* __restrict__ T1,
    const float* __restrict__ w2, const float* __restrict__ b2,
    float* __restrict__ d2, int row0)
{
  int bid = blockIdx.x;
  int ch = bid & 1; bid >>= 1;
  int side = bid & 3; bid >>= 2;
  int n = bid;
  bool hside = side < 2;
  int rbase = (side == 1) ? 62 : 0;   // d1 rows for h-sides
  int cbase = (side == 3) ? 62 : 0;   // d1 cols for v-sides
  __shared__ int sE[128];
  __shared__ float sD[32 * 128];      // [ci][strip]
  int tid = threadIdx.x;
  if (tid < 128) {
    int yy, xx;
    if (hside) { yy = rbase + (tid >> 6); xx = tid & 63; }
    else       { yy = tid >> 1; xx = cbase + (tid & 1); }
    sE[tid] = idx[row0 + (n << 12) + yy * 64 + xx];
  }
  __syncthreads();
  for (int t = tid; t < 32 * 128; t += 256) {
    int ci = t >> 7, j = t & 127;
    sD[t] = T1[sE[j] * 32 + ci];
  }
  __syncthreads();
  int px = tid & 127, q = tid >> 7;
  int co0 = (ch * 2 + q) * 16;
  int u, v;
  if (side == 0)      { u = 0;   v = px; }
  else if (side == 1) { u = 127; v = px; }
  else if (side == 2) { u = px;  v = 0;   if (px == 0 || px == 127) return; }
  else                { u = px;  v = 127; if (px == 0 || px == 127) return; }
  float acc[16];
#pragma unroll
  for (int j = 0; j < 16; ++j) acc[j] = 0.f;
  for (int ci = 0; ci < 32; ++ci) {
    const float* P = sD + ci * 128;
    float u9[9];
#pragma unroll
    for (int dy = -1; dy <= 1; ++dy)
#pragma unroll
      for (int dx = -1; dx <= 1; ++dx) {
        int uy = u + dy, ux = v + dx;
        float val = 0.f;
        if (uy >= 0 && uy < 128 && ux >= 0 && ux < 128) {
          int ky0, ky1, kx0, kx1; float ay0, ax0;
          if (uy & 1) { ky0 = uy >> 1; ky1 = ky0 + 1; ay0 = .75f; }
          else        { ky1 = uy >> 1; ky0 = ky1 - 1; ay0 = .25f; }
          if (ux & 1) { kx0 = ux >> 1; kx1 = kx0 + 1; ax0 = .75f; }
          else        { kx1 = ux >> 1; kx0 = kx1 - 1; ax0 = .25f; }
          ky0 = ky0 < 0 ? 0 : (ky0 > 63 ? 63 : ky0);
          ky1 = ky1 < 0 ? 0 : (ky1 > 63 ? 63 : ky1);
          kx0 = kx0 < 0 ? 0 : (kx0 > 63 ? 63 : kx0);
          kx1 = kx1 < 0 ? 0 : (kx1 > 63 ? 63 : kx1);
          int i00, i01, i10, i11;
          if (hside) {
            i00 = (ky0 - rbase) * 64 + kx0; i01 = (ky0 - rbase) * 64 + kx1;
            i10 = (ky1 - rbase) * 64 + kx0; i11 = (ky1 - rbase) * 64 + kx1;
          } else {
            i00 = ky0 * 2 + (kx0 - cbase); i01 = ky0 * 2 + (kx1 - cbase);
            i10 = ky1 * 2 + (kx0 - cbase); i11 = ky1 * 2 + (kx1 - cbase);
          }
          float ay1 = 1.f - ay0, ax1 = 1.f - ax0;
          val = ay0 * (ax0 * P[i00] + ax1 * P[i01]) +
                ay1 * (ax0 * P[i10] + ax1 * P[i11]);
        }
        u9[(dy + 1) * 3 + (dx + 1)] = val;
      }
#pragma unroll
    for (int j = 0; j < 16; ++j) {
      const float* wp = w2 + ((size_t)((co0 + j) * 32 + ci)) * 9;
#pragma unroll
      for (int tp = 0; tp < 9; ++tp) acc[j] += u9[tp] * wp[tp];
    }
  }
#pragma unroll
  for (int j = 0; j < 16; ++j) {
    int co = co0 + j;
    float val = acc[j] + b2[co];
    val = val > 0.f ? val : 0.f;
    d2[((size_t)(n * 64 + co) * 128 + u) * 128 + v] = val;
  }
}

// ---------- recon interior: composed conv, 32x16 tiles, 128-thr blocks ----------
__global__ __launch_bounds__(128) void k_upconv2x_b(
    const float* __restrict__ I, const float* __restrict__ k2,
    const float* __restrict__ bias, float* __restrict__ O, int n0)
{
  constexpr int Hi = 128, Ci = 64, Co = 3;
  int bid = blockIdx.x;
  int tx = bid & 3; bid >>= 2;       // 4 x-tiles of 32
  int ty = bid & 7; bid >>= 3;       // 8 y-tiles of 16
  int n = bid;
  int Y0 = ty * 16, X0 = tx * 32;
  __shared__ float sI[4][18 * 35];
  int tid = threadIdx.x;
  int lx = tid & 15, ly = tid >> 4;  // 16x8 threads, 2x2 low-res px each
  float4 acc[3][2][2];
#pragma unroll
  for (int j = 0; j < 3; ++j)
#pragma unroll
    for (int a = 0; a < 2; ++a)
#pragma unroll
      for (int b = 0; b < 2; ++b) acc[j][a][b] = make_float4(0.f, 0.f, 0.f, 0.f);
  for (int c0 = 0; c0 < Ci; c0 += 4) {
    __syncthreads();
    for (int i = tid; i < 4 * 18 * 34; i += 128) {
      int s = i / 612, r2 = i % 612;
      int rr = r2 / 34, cc2 = r2 % 34;
      int gy = Y0 - 1 + rr; gy = gy < 0 ? 0 : (gy > Hi - 1 ? Hi - 1 : gy);
      int gx = X0 - 1 + cc2; gx = gx < 0 ? 0 : (gx > Hi - 1 ? Hi - 1 : gx);
      sI[s][rr * 35 + cc2] = I[((size_t)n * Ci + c0 + s) * Hi * Hi + gy * Hi + gx];
    }
    __syncthreads();
#pragma unroll
    for (int s = 0; s < 4; ++s) {
      float t[4][4];
#pragma unroll
      for (int r = 0; r < 4; ++r)
#pragma unroll
        for (int c = 0; c < 4; ++c)
          t[r][c] = sI[s][(2 * ly + r) * 35 + 2 * lx + c];
#pragma unroll
      for (int j = 0; j < 3; ++j) {
        const float* kj = k2 + ((size_t)j * Ci + c0 + s) * 36;
#pragma unroll
        for (int a = 0; a < 3; ++a)
#pragma unroll
          for (int b = 0; b < 3; ++b) {
            float w00 = kj[a * 3 + b];
            float w01 = kj[9 + a * 3 + b];
            float w10 = kj[18 + a * 3 + b];
            float w11 = kj[27 + a * 3 + b];
#pragma unroll
            for (int pyy = 0; pyy < 2; ++pyy) {
              float i0 = t[pyy + a][b];
              float i1 = t[pyy + a][b + 1];
              acc[j][pyy][0].x += i0 * w00;
              acc[j][pyy][0].y += i0 * w01;
              acc[j][pyy][0].z += i1 * w00;
              acc[j][pyy][0].w += i1 * w01;
              acc[j][pyy][1].x += i0 * w10;
              acc[j][pyy][1].y += i0 * w11;
              acc[j][pyy][1].z += i1 * w10;
              acc[j][pyy][1].w += i1 * w11;
            }
          }
      }
    }
  }
  int ox = 2 * X0 + 4 * lx;
#pragma unroll
  for (int j = 0; j < 3; ++j) {
    float bv = bias[j];
#pragma unroll
    for (int pyy = 0; pyy < 2; ++pyy) {
      int oy0 = 2 * (Y0 + 2 * ly + pyy);
#pragma unroll
      for (int py = 0; py < 2; ++py) {
        float4 v = acc[j][pyy][py];
        v.x += bv; v.y += bv; v.z += bv; v.w += bv;
        size_t off = (((size_t)((n0 + n) * Co + j)) * 256 + oy0 + py) * 256 + ox;
        *(float4*)&O[off] = v;
      }
    }
  }
}

// ---------- exact recon border ring via d2-strip LDS ----------
// grid: (n*4 + side); 256 thr = px. ci staged in 2 halves of 32.
__global__ __launch_bounds__(256) void k_border_b(
    const float* __restrict__ d2, const float* __restrict__ w3,
    const float* __restrict__ b3, float* __restrict__ O, int n0)
{
  int bid = blockIdx.x;
  int side = bid & 3; int n = bid >> 2;
  bool hside = side < 2;
  int rbase = (side == 1) ? 126 : 0;
  int cbase = (side == 3) ? 126 : 0;
  __shared__ float sD[32 * 256];  // [ci][strip]
  int tid = threadIdx.x;
  int px = tid;
  int u, v;
  if (side == 0)      { u = 0;   v = px; }
  else if (side == 1) { u = 255; v = px; }
  else if (side == 2) { u = px;  v = 0; }
  else                { u = px;  v = 255; }
  bool active = hside || (px != 0 && px != 255);
  float a0 = 0.f, a1 = 0.f, a2 = 0.f;
  for (int half = 0; half < 2; ++half) {
    __syncthreads();
    int cib = half * 32;
    for (int t = tid; t < 32 * 256; t += 256) {
      int ci = t >> 8, j = t & 255;
      int yy, xx;
      if (hside) { yy = rbase + (j >> 7); xx = j & 127; }
      else       { yy = j >> 1; xx = cbase + (j & 1); }
      sD[t] = d2[(((size_t)n * 64 + cib + ci) * 128 + yy) * 128 + xx];
    }
    __syncthreads();
    if (active) {
      for (int ci = 0; ci < 32; ++ci) {
        const float* P = sD + ci * 256;
        float u9[9];
#pragma unroll
        for (int dy = -1; dy <= 1; ++dy)
#pragma unroll
          for (int dx = -1; dx <= 1; ++dx) {
            int uy = u + dy, ux = v + dx;
            float val = 0.f;
            if (uy >= 0 && uy < 256 && ux >= 0 && ux < 256) {
              int ky0, ky1, kx0, kx1; float ay0, ax0;
              if (uy & 1) { ky0 = uy >> 1; ky1 = ky0 + 1; ay0 = .75f; }
              else        { ky1 = uy >> 1; ky0 = ky1 - 1; ay0 = .25f; }
              if (ux & 1) { kx0 = ux >> 1; kx1 = kx0 + 1; ax0 = .75f; }
              else        { kx1 = ux >> 1; kx0 = kx1 - 1; ax0 = .25f; }
              ky0 = ky0 < 0 ? 0 : (ky0 > 127 ? 127 : ky0);
              ky1 = ky1 < 0 ? 0 : (ky1 > 127 ? 127 : ky1);
              kx0 = kx0 < 0 ? 0 : (kx0 > 127 ? 127 : kx0);
              kx1 = kx1 < 0 ? 0 : (kx1 > 127 ? 127 : kx1);
              int i00, i01, i10, i11;
              if (hside) {
                i00 = (ky0 - rbase) * 128 + kx0; i01 = (ky0 - rbase) * 128 + kx1;
                i10 = (ky1 - rbase) * 128 + kx0; i11 = (ky1 - rbase) * 128 + kx1;
              } else {
                i00 = ky0 * 2 + (kx0 - cbase); i01 = ky0 * 2 + (kx1 - cbase);
                i10 = ky1 * 2 + (kx0 - cbase); i11 = ky1 * 2 + (kx1 - cbase);
              }
              float ay1 = 1.f - ay0, ax1 = 1.f - ax0;
              val = ay0 * (ax0 * P[i00] + ax1 * P[i01]) +
                    ay1 * (ax0 * P[i10] + ax1 * P[i11]);
            }
            u9[(dy + 1) * 3 + (dx + 1)] = val;
          }
        const float* w0 = w3 + ((size_t)(0 * 64 + cib + ci)) * 9;
        const float* w1 = w3 + ((size_t)(1 * 64 + cib + ci)) * 9;
        const float* w2p = w3 + ((size_t)(2 * 64 + cib + ci)) * 9;
#pragma unroll
        for (int tp = 0; tp < 9; ++tp) {
          a0 += u9[tp] * w0[tp];
          a1 += u9[tp] * w1[tp];
          a2 += u9[tp] * w2p[tp];
        }
      }
    }
  }
  if (active) {
    size_t b = ((size_t)(n0 + n) * 3) * 65536 + (size_t)u * 256 + v;
    O[b] = a0 + b3[0];
    O[b + 65536] = a1 + b3[1];
    O[b + 131072] = a2 + b3[2];
  }
}

extern "C" void kernel_launch(void* const* d_in, const int* in_sizes, int n_in,
                              void* d_out, int out_size, void* d_ws, size_t ws_size,
                              hipStream_t stream)
{
  const float* x      = (const float*)d_in[0];
  const float* cb     = (const float*)d_in[1];
  const float* enc_w1 = (const float*)d_in[2];
  const float* enc_b1 = (const float*)d_in[3];
  const float* enc_w2 = (const float*)d_in[4];
  const float* enc_b2 = (const float*)d_in[5];
  const float* enc_w3 = (const float*)d_in[6];
  const float* enc_b3 = (const float*)d_in[7];
  const float* dec_w1 = (const float*)d_in[8];
  const float* dec_b1 = (const float*)d_in[9];
  const float* dec_w2 = (const float*)d_in[10];
  const float* dec_b2 = (const float*)d_in[11];
  const float* dec_w3 = (const float*)d_in[12];
  const float* dec_b3 = (const float*)d_in[13];

  float* ws = (float*)d_ws;
  float* lossA = ws;
  int* idx = (int*)(lossA + 64);
  unsigned long long* pk = (unsigned long long*)(idx + ROWS);
  float* k2a = (float*)(pk + ROWS);
  float* k2b = k2a + K2A_FLOATS;
  float* T1  = k2b + K2B_FLOATS;
  float* G   = T1 + T1_FLOATS;
  float* chunkbuf = G + G_FLOATS + 64;

  int CH = 1;
  for (int c = 32; c >= 1; c >>= 1) {
    size_t need = ((size_t)FIX_FLOATS + (size_t)(H1_PER_N + Z_PER_N + H2_PER_N) * c) * 4;
    if (need <= ws_size) { CH = c; break; }
  }
  float* h1 = chunkbuf;                   // d2 buffer
  float* z  = h1 + (size_t)H1_PER_N * CH;
  float* h2 = z + (size_t)Z_PER_N * CH;

  k_init<<<ROWS / 256, 256, 0, stream>>>(lossA, pk);
  k_wtrans<<<(64 * 32 + 255) / 256, 256, 0, stream>>>(dec_w2, k2a, 64 * 32);
  k_wtrans<<<1, 256, 0, stream>>>(dec_w3, k2b, 3 * 64);
  k_gtab1<<<64, 256, 0, stream>>>(cb, dec_w1, dec_b1, T1);
  k_gtab2<<<Kc, 256, 0, stream>>>(k2a, T1, G);

  float* out = (float*)d_out;

  for (int n0 = 0; n0 < Bn; n0 += CH) {
    int row0 = n0 * H2 * W2;
    k_conv1<<<CH * 128, 256, 0, stream>>>(x, enc_w1, enc_b1, h1, n0);
    k_conv2<<<CH * 32, 256, 0, stream>>>(h1, enc_w2, enc_b2, h2);
    k_conv3z<<<CH * 64, 256, 0, stream>>>(h2, enc_w3, enc_b3, z);
    k_vq<<<CH * 16 * 4, 256, 0, stream>>>(z, cb, pk, row0);
    k_vqfin<<<CH * 16, 256, 0, stream>>>(z, cb, pk, idx, lossA, row0);
    // d2 interior (composed) then exact ring
    k_upg<<<CH * 8 * 16, 256, 0, stream>>>(idx, G, dec_b2, h1, row0);
    k_border_a<<<CH * 4 * 2, 256, 0, stream>>>(idx, T1, dec_w2, dec_b2, h1, row0);
    // recon interior (composed) then exact ring
    k_upconv2x_b<<<CH * 32, 128, 0, stream>>>(h1, k2b, dec_b3, out + 2, n0);
    k_border_b<<<CH * 4, 256, 0, stream>>>(h1, dec_w3, dec_b3, out + 2, n0);
  }
  k_loss_final<<<1, 64, 0, stream>>>(lossA, out);
}